// Round 3
// baseline (319.600 us; speedup 1.0000x reference)
//
#include <hip/hip_runtime.h>
#include <math.h>

#define Bx 8
#define IMG 128
#define DD 128
#define HEADS 4
#define LL 2
#define PCc 8
#define PFf 4
#define HCc 16
#define NCc 256
#define HFf 32
#define NFf 1024
#define NTOK 1280
#define HD 32
#define SPLIT 2          // key-split factor for flash-decode attention
#define NSTG 10          // stages per split = NTOK/64/SPLIT
#define NQT 20           // NTOK/64 query tiles
#define MEGA1_GRID 768
#define NLEAF 32

typedef __attribute__((ext_vector_type(8))) short short8;
typedef __attribute__((ext_vector_type(4))) float f32x4;

__device__ __forceinline__ short f2bf(float f) {
  unsigned u = __builtin_bit_cast(unsigned, f);
  u += 0x7FFF + ((u >> 16) & 1);   // RNE
  return (short)(u >> 16);
}
__device__ __forceinline__ float bf2f(short s) {
  unsigned u = ((unsigned)(unsigned short)s) << 16;
  return __builtin_bit_cast(float, u);
}

// ---------------- device-scope tree grid-barrier (per-XCD L2 non-coherence
// handled by threadfence release + acquire fence; agent-scope atomics hit the
// common coherence point). bar layout: [0]=gen, [1..32]=leaf, [33]=root.
// Slot is zero-initialized by block 0 at kernel entry (arrivals happen only
// after >=10us of phase work, so the init is safely ordered).
__device__ __forceinline__ void grid_barrier(int* bar, int nblk) {
  __syncthreads();
  if (threadIdx.x == 0) {
    __threadfence();   // flush this XCD's dirty L2 lines (release)
    int g = __hip_atomic_load(&bar[0], __ATOMIC_RELAXED, __HIP_MEMORY_SCOPE_AGENT);
    int leaf = blockIdx.x & (NLEAF - 1);
    int v = __hip_atomic_fetch_add(&bar[1 + leaf], 1, __ATOMIC_ACQ_REL,
                                   __HIP_MEMORY_SCOPE_AGENT);
    if (v == nblk / NLEAF - 1) {
      int r = __hip_atomic_fetch_add(&bar[33], 1, __ATOMIC_ACQ_REL,
                                     __HIP_MEMORY_SCOPE_AGENT);
      if (r == NLEAF - 1)
        __hip_atomic_fetch_add(&bar[0], 1, __ATOMIC_RELEASE,
                               __HIP_MEMORY_SCOPE_AGENT);
    }
    while (__hip_atomic_load(&bar[0], __ATOMIC_RELAXED,
                             __HIP_MEMORY_SCOPE_AGENT) == g)
      __builtin_amdgcn_s_sleep(2);
    __builtin_amdgcn_fence(__ATOMIC_ACQUIRE, "agent");  // invalidate L1/L2
  }
  __syncthreads();
}

__device__ __forceinline__ void bar_init(int* bar) {
  if (blockIdx.x == 0 && threadIdx.x < 40)
    __hip_atomic_store(&bar[threadIdx.x], 0, __ATOMIC_RELAXED,
                       __HIP_MEMORY_SCOPE_AGENT);
}

// ---------------- mega1: prologue (weights/sobel/coarse/fine) + grid barrier
// + edge sort. 768 persistent blocks, tiny LDS -> high occupancy for the
// memory-bound prologue phase.
__global__ __launch_bounds__(256, 4) void k_mega1(const float* __restrict__ x,
    const float* __restrict__ Wpc, const float* __restrict__ bpc,
    const float* __restrict__ Wpf, const float* __restrict__ bpf,
    const float* __restrict__ te,
    const float* __restrict__ Wqkv, const float* __restrict__ Wo,
    const float* __restrict__ W1, const float* __restrict__ W2,
    short* __restrict__ WtQKV, short* __restrict__ WtO,
    short* __restrict__ Wt1, short* __restrict__ Wt2,
    float* __restrict__ e, float* __restrict__ tokens,
    float* __restrict__ fineb, int* __restrict__ order,
    float* __restrict__ msort, int* __restrict__ bars) {
  __shared__ float sob[256];
  __shared__ float patc[2][PCc * PCc];
  __shared__ float patf[2][PFf * PFf];
  __shared__ float wsumf[4];
  __shared__ int wtot[4];
  bar_init(bars);
  int bid = blockIdx.x;
  int t = threadIdx.x;

  // ---- phase P: prologue over 6656 virtual blocks
  for (int vb = bid; vb < 6656; vb += MEGA1_GRID) {
    __syncthreads();   // LDS reuse guard between virtual blocks
    if (vb < 1024) {
      // ---- weight prep: transpose + bf16
      int idx = vb * 256 + t;   // 0 .. 262143
      int l = idx / 131072, r = idx % 131072;
      const float* src; short* dst; int N, off;
      if (r < 49152)      { src = Wqkv + l * 49152; dst = WtQKV + l * 49152; N = 384; off = r; }
      else if (r < 65536) { src = Wo + l * 16384;  dst = WtO + l * 16384;  N = 128; off = r - 49152; }
      else if (r < 98304) { src = W1 + l * 32768;  dst = Wt1 + l * 32768;  N = 256; off = r - 65536; }
      else                { src = W2 + l * 32768;  dst = Wt2 + l * 32768;  N = 128; off = r - 98304; }
      int k = off / N, n = off % N;
      int K = (r >= 98304) ? 256 : 128;
      dst[(size_t)n * K + k] = f2bf(src[off]);
    } else if (vb < 1536) {
      // ---- sobel + 4x4 avgpool -> cell energy
      int bt = vb - 1024;
      int b = bt >> 6, tile = bt & 63;
      int ty = tile >> 3, tx = tile & 7;
      int ly = t >> 4, lx = t & 15;
      int py = ty * 16 + ly, px = tx * 16 + lx;
      const float* img = x + (size_t)b * IMG * IMG;
      float v[3][3];
      #pragma unroll
      for (int ky = 0; ky < 3; ++ky)
        #pragma unroll
        for (int kx = 0; kx < 3; ++kx) {
          int yy = py + ky - 1, xx = px + kx - 1;
          v[ky][kx] = (yy >= 0 && yy < IMG && xx >= 0 && xx < IMG)
                          ? img[yy * IMG + xx] : 0.f;
        }
      float gx = -v[0][0] + v[0][2] - 2.f * v[1][0] + 2.f * v[1][2] - v[2][0] + v[2][2];
      float gy = -v[0][0] - 2.f * v[0][1] - v[0][2] + v[2][0] + 2.f * v[2][1] + v[2][2];
      sob[t] = sqrtf(gx * gx + gy * gy);
      __syncthreads();
      if (t < 16) {
        int cy = t >> 2, cx = t & 3;
        float s = 0.f;
        #pragma unroll
        for (int dy = 0; dy < 4; ++dy)
          #pragma unroll
          for (int dx = 0; dx < 4; ++dx) s += sob[(cy * 4 + dy) * 16 + cx * 4 + dx];
        e[b * NFf + (ty * 4 + cy) * 32 + tx * 4 + cx] = s * (1.f / 16.f);
      }
    } else if (vb < 2560) {
      // ---- coarse patch embed, 2 tokens per block
      int bt = (vb - 1536) * 2 + (t >> 7);
      int b = bt / NCc, tok = bt % NCc;
      int hc = tok / HCc, wc = tok % HCc;
      int half = t >> 7, d = t & 127;
      if (d < PCc * PCc) {
        int pi = d / PCc, pj = d % PCc;
        patc[half][d] = x[(b * IMG + hc * PCc + pi) * IMG + wc * PCc + pj];
      }
      __syncthreads();
      float acc = bpc[d] + te[d];
      #pragma unroll 8
      for (int i = 0; i < PCc * PCc; ++i) acc += patc[half][i] * Wpc[i * DD + d];
      tokens[(size_t)(b * NTOK + tok) * DD + d] = acc;
    } else {
      // ---- fine patch embed, 2 tokens per block -> fineb
      int ft = (vb - 2560) * 2 + (t >> 7);
      int b = ft >> 10, tloc = ft & 1023;
      int hf = tloc >> 5, wf = tloc & 31;
      int half = t >> 7, d = t & 127;
      if (d < PFf * PFf) {
        int pi = d / PFf, pj = d % PFf;
        patf[half][d] = x[(b * IMG + hf * PFf + pi) * IMG + wf * PFf + pj];
      }
      __syncthreads();
      float acc = bpf[d];
      #pragma unroll
      for (int i = 0; i < PFf * PFf; ++i) acc += patf[half][i] * Wpf[i * DD + d];
      fineb[(size_t)(b * NFf + tloc) * DD + d] = acc;
    }
  }

  grid_barrier(bars, MEGA1_GRID);

  // ---- phase S: edge sort (8 images, 256 threads: 4 cells/thread)
  if (bid < 8) {
    int b = bid;
    int lane = t & 63, wave = t >> 6;
    float ev[4]; int mm[4];
    float s4 = 0.f;
    #pragma unroll
    for (int i = 0; i < 4; ++i) { ev[i] = e[b * NFf + t * 4 + i]; s4 += ev[i]; }
    float r = s4;
    #pragma unroll
    for (int o = 32; o > 0; o >>= 1) r += __shfl_xor(r, o, 64);
    if (lane == 0) wsumf[wave] = r;
    __syncthreads();
    float tot = wsumf[0] + wsumf[1] + wsumf[2] + wsumf[3];
    float mean = tot * (1.f / 1024.f);
    int mcnt = 0;
    #pragma unroll
    for (int i = 0; i < 4; ++i) { mm[i] = (ev[i] > mean) ? 1 : 0; mcnt += mm[i]; }
    int incl = mcnt;
    #pragma unroll
    for (int o = 1; o < 64; o <<= 1) {
      int u = __shfl_up(incl, o, 64);
      if (lane >= o) incl += u;
    }
    if (lane == 63) wtot[wave] = incl;
    __syncthreads();
    int wbase = 0, totE = 0;
    #pragma unroll
    for (int i = 0; i < 4; ++i) {
      int c = wtot[i];
      if (i < wave) wbase += c;
      totE += c;
    }
    int ebase = wbase + incl - mcnt;   // edges strictly before cell t*4
    #pragma unroll
    for (int i = 0; i < 4; ++i) {
      int c = t * 4 + i;
      int pos = mm[i] ? ebase : (totE + c - ebase);
      order[b * NFf + pos] = c;
      msort[b * NFf + pos] = (float)mm[i];
      ebase += mm[i];
    }
  }
}

// ---------------- gather + LN1 + layer-0 QKV GEMM, 32 rows/block
__global__ __launch_bounds__(256) void k_gather_qkv(float* __restrict__ tokens,
    const float* __restrict__ fineb, const int* __restrict__ order,
    const float* __restrict__ msort, const float* __restrict__ te,
    const float* __restrict__ g, const float* __restrict__ bb,
    const short* __restrict__ WtQ, short* __restrict__ qkvb) {
  __shared__ short Blds[128 * 128];
  __shared__ short Ylds[32 * 136];
  int row0 = blockIdx.x * 32;
  int t = threadIdx.x;
  int lane = t & 63, w = t >> 6;
  int m = lane & 15, quad = lane >> 4;
  int rt = w >> 1, ch = w & 1;
  int lrow = lane >> 4, jphys = lane & 15;
  f32x4 zero = {0.f, 0.f, 0.f, 0.f};

  // ---- issue QKV chunk-0 weight DMA now; drains at the first barrier
  #pragma unroll
  for (int j = 0; j < 8; ++j) {
    int c = j * 4 + w;
    int r = c * 4 + lrow;
    int jlog = jphys ^ (r & 15);
    __builtin_amdgcn_global_load_lds(
        (const unsigned*)&WtQ[(size_t)r * 128 + jlog * 8],
        (unsigned*)&Blds[c * 512], 16, 0, 0);
  }
  // ---- phase A: gather + LN1 -> Ylds (8 rows per wave)
  float2 gg = ((const float2*)g)[lane];
  float2 bv = ((const float2*)bb)[lane];
  #pragma unroll
  for (int rr = 0; rr < 8; ++rr) {
    int lr = w * 8 + rr;
    int row = row0 + lr;
    int b = row / NTOK, rl = row % NTOK;
    float2 v;
    if (rl < NCc) {
      v = ((const float2*)(tokens + (size_t)row * DD))[lane];
    } else {
      int pos = rl - NCc;
      int src = order[b * NFf + pos];
      float mk = msort[b * NFf + pos];
      float2 u = ((const float2*)(fineb + (size_t)(b * NFf + src) * DD))[lane];
      float2 tv = ((const float2*)(te + DD))[lane];
      v.x = u.x * mk + tv.x;
      v.y = u.y * mk + tv.y;
      ((float2*)(tokens + (size_t)row * DD))[lane] = v;
    }
    float s = v.x + v.y;
    #pragma unroll
    for (int o = 32; o > 0; o >>= 1) s += __shfl_xor(s, o, 64);
    float mean = s * (1.f / 128.f);
    float cx = v.x - mean, cy = v.y - mean;
    float q = cx * cx + cy * cy;
    #pragma unroll
    for (int o = 32; o > 0; o >>= 1) q += __shfl_xor(q, o, 64);
    float rstd = rsqrtf(q * (1.f / 128.f) + 1e-5f);
    int p = (int)(unsigned short)f2bf(cx * rstd * gg.x + bv.x)
          | ((int)(unsigned short)f2bf(cy * rstd * gg.y + bv.y) << 16);
    ((int*)Ylds)[lr * 68 + lane] = p;
  }
  // ---- phase B: QKV GEMM, 3 chunks of 128 output cols
  for (int c3 = 0; c3 < 3; ++c3) {
    if (c3) {
      __syncthreads();
      #pragma unroll
      for (int j = 0; j < 8; ++j) {
        int c = j * 4 + w;
        int r = c * 4 + lrow;
        int jlog = jphys ^ (r & 15);
        __builtin_amdgcn_global_load_lds(
            (const unsigned*)&WtQ[(size_t)(c3 * 128 + r) * 128 + jlog * 8],
            (unsigned*)&Blds[c * 512], 16, 0, 0);
      }
    }
    __syncthreads();
    f32x4 qa[4] = {zero, zero, zero, zero};
    #pragma unroll
    for (int ks = 0; ks < 4; ++ks) {
      short8 af = *(const short8*)&Ylds[(rt * 16 + m) * 136 + quad * 8 + ks * 32];
      int pc = ((quad + ks * 4) ^ m) * 8;
      #pragma unroll
      for (int nt = 0; nt < 4; ++nt) {
        short8 bf = *(const short8*)&Blds[(ch * 64 + nt * 16 + m) * 128 + pc];
        qa[nt] = __builtin_amdgcn_mfma_f32_16x16x32_bf16(af, bf, qa[nt], 0, 0, 0);
      }
    }
    #pragma unroll
    for (int nt = 0; nt < 4; ++nt) {
      int col = c3 * 128 + ch * 64 + nt * 16 + m;
      #pragma unroll
      for (int r = 0; r < 4; ++r) {
        int row = row0 + rt * 16 + quad * 4 + r;
        qkvb[(size_t)row * 384 + col] = f2bf(qa[nt][r]);
      }
    }
  }
}

// ---------------- fused transformer tail body (one layer, 32 rows/block)
__device__ __forceinline__ void fused_body(int row0,
    const short* __restrict__ Opart, const float* __restrict__ Lpart,
    const short* __restrict__ WtO, const float* __restrict__ bo_,
    const float* __restrict__ ln2g_, const float* __restrict__ ln2b_,
    const short* __restrict__ Wt1, const float* __restrict__ b1_,
    const short* __restrict__ Wt2, const float* __restrict__ b2_,
    float* __restrict__ tokens, const float* __restrict__ ln1g_,
    const float* __restrict__ ln1b_, const short* __restrict__ WtQ,
    short* __restrict__ qkvb, const float* __restrict__ dWc_,
    const float* __restrict__ dbc_, const float* __restrict__ dWf_,
    const float* __restrict__ dbf_, float* __restrict__ hrow) {
  __shared__ short Blds[128 * 128];
  __shared__ short AH[32 * 268];
  __shared__ short Ylds[32 * 136];
  __shared__ float pls[2][32], plq[2][32];
  int b = row0 / NTOK;
  int rloc = row0 % NTOK;
  int qt = rloc >> 6, qoff = rloc & 63;
  int t = threadIdx.x;
  int lane = t & 63, w = t >> 6;
  int m = lane & 15, quad = lane >> 4;
  int rt = w >> 1, ch = w & 1;
  int lrow = lane >> 4, jphys = lane & 15;
  f32x4 zero = {0.f, 0.f, 0.f, 0.f};

  // ---- Wo B staging (DMA), overlaps A combine below
  #pragma unroll
  for (int j = 0; j < 8; ++j) {
    int c = j * 4 + w;
    int r = c * 4 + lrow;
    int jlog = jphys ^ (r & 15);
    __builtin_amdgcn_global_load_lds(
        (const unsigned*)&WtO[(size_t)r * 128 + jlog * 8],
        (unsigned*)&Blds[c * 512], 16, 0, 0);
  }
  // ---- A staging: combine split-K attention partials, normalize by L
  #pragma unroll
  for (int it = 0; it < 2; ++it) {
    int idx = t + it * 256;
    int q = idx >> 4, j = idx & 15;
    int dh = j >> 2, dd = (j & 3) * 8;
    int qg = qoff + q;
    size_t pb = ((size_t)(b * HEADS + dh) * NQT + qt) * SPLIT;
    float L = 0.f;
    #pragma unroll
    for (int sk = 0; sk < SPLIT; ++sk) L += Lpart[(pb + sk) * 64 + qg];
    float o[8] = {0, 0, 0, 0, 0, 0, 0, 0};
    #pragma unroll
    for (int sk = 0; sk < SPLIT; ++sk) {
      short8 po = *(const short8*)&Opart[(pb + sk) * 2048 + qg * 32 + dd];
      #pragma unroll
      for (int i = 0; i < 8; ++i) o[i] += bf2f(po[i]);
    }
    float rs = 1.f / L;
    short8 ov;
    #pragma unroll
    for (int i = 0; i < 8; ++i) ov[i] = f2bf(o[i] * rs);
    *(short8*)&AH[q * 136 + j * 8] = ov;
  }
  __syncthreads();
  // ---- Wo GEMM
  f32x4 acc[4] = {zero, zero, zero, zero};
  #pragma unroll
  for (int ks = 0; ks < 4; ++ks) {
    short8 af = *(const short8*)&AH[(rt * 16 + m) * 136 + quad * 8 + ks * 32];
    int pc = ((quad + ks * 4) ^ m) * 8;
    #pragma unroll
    for (int nt = 0; nt < 4; ++nt) {
      short8 bf = *(const short8*)&Blds[(ch * 64 + nt * 16 + m) * 128 + pc];
      acc[nt] = __builtin_amdgcn_mfma_f32_16x16x32_bf16(af, bf, acc[nt], 0, 0, 0);
    }
  }
  // ---- residual (register-carried) + LN2 stats
  float v[4][4];
  #pragma unroll
  for (int nt = 0; nt < 4; ++nt) {
    int col = ch * 64 + nt * 16 + m;
    float bv = bo_[col];
    #pragma unroll
    for (int r = 0; r < 4; ++r) {
      int row = row0 + rt * 16 + quad * 4 + r;
      v[nt][r] = acc[nt][r] + bv + tokens[(size_t)row * DD + col];
    }
  }
  #pragma unroll
  for (int r = 0; r < 4; ++r) {
    float s = v[0][r] + v[1][r] + v[2][r] + v[3][r];
    float q = v[0][r] * v[0][r] + v[1][r] * v[1][r]
            + v[2][r] * v[2][r] + v[3][r] * v[3][r];
    #pragma unroll
    for (int o = 1; o < 16; o <<= 1) { s += __shfl_xor(s, o); q += __shfl_xor(q, o); }
    if (m == 0) {
      int lr = rt * 16 + quad * 4 + r;
      pls[ch][lr] = s;
      plq[ch][lr] = q;
    }
  }
  __syncthreads();
  // ---- W1 half-0 DMA now (overlaps LN2 apply)
  #pragma unroll
  for (int j = 0; j < 8; ++j) {
    int c = j * 4 + w;
    int r = c * 4 + lrow;
    int jlog = jphys ^ (r & 15);
    __builtin_amdgcn_global_load_lds(
        (const unsigned*)&Wt1[(size_t)r * 128 + jlog * 8],
        (unsigned*)&Blds[c * 512], 16, 0, 0);
  }
  // ---- LN2 apply -> Ylds
  #pragma unroll
  for (int r = 0; r < 4; ++r) {
    int lr = rt * 16 + quad * 4 + r;
    float S = pls[0][lr] + pls[1][lr];
    float Q = plq[0][lr] + plq[1][lr];
    float mean = S * (1.f / 128.f);
    float var = Q * (1.f / 128.f) - mean * mean;
    float rstd = rsqrtf(var + 1e-5f);
    #pragma unroll
    for (int nt = 0; nt < 4; ++nt) {
      int col = ch * 64 + nt * 16 + m;
      Ylds[lr * 136 + col] = f2bf((v[nt][r] - mean) * rstd * ln2g_[col] + ln2b_[col]);
    }
  }
  // ---- MLP: h = gelu(y @ W1 + b1) -> AH (stride 268)
  for (int hh = 0; hh < 2; ++hh) {
    if (hh) {
      __syncthreads();
      #pragma unroll
      for (int j = 0; j < 8; ++j) {
        int c = j * 4 + w;
        int r = c * 4 + lrow;
        int jlog = jphys ^ (r & 15);
        __builtin_amdgcn_global_load_lds(
            (const unsigned*)&Wt1[(size_t)(128 + r) * 128 + jlog * 8],
            (unsigned*)&Blds[c * 512], 16, 0, 0);
      }
    }
    __syncthreads();
    f32x4 ha[4] = {zero, zero, zero, zero};
    #pragma unroll
    for (int ks = 0; ks < 4; ++ks) {
      short8 af = *(const short8*)&Ylds[(rt * 16 + m) * 136 + quad * 8 + ks * 32];
      int pc = ((quad + ks * 4) ^ m) * 8;
      #pragma unroll
      for (int nt = 0; nt < 4; ++nt) {
        short8 bf = *(const short8*)&Blds[(ch * 64 + nt * 16 + m) * 128 + pc];
        ha[nt] = __builtin_amdgcn_mfma_f32_16x16x32_bf16(af, bf, ha[nt], 0, 0, 0);
      }
    }
    #pragma unroll
    for (int nt = 0; nt < 4; ++nt) {
      int n = hh * 128 + ch * 64 + nt * 16 + m;
      float bv = b1_[n];
      #pragma unroll
      for (int r = 0; r < 4; ++r) {
        float vv = ha[nt][r] + bv;
        vv = 0.5f * vv * (1.f + erff(vv * 0.70710678118654752f));
        AH[(rt * 16 + quad * 4 + r) * 268 + n] = f2bf(vv);
      }
    }
  }
  // ---- W2: K=256 in two chunks
  f32x4 a2[4] = {zero, zero, zero, zero};
  for (int kb = 0; kb < 2; ++kb) {
    __syncthreads();
    #pragma unroll
    for (int j = 0; j < 8; ++j) {
      int c = j * 4 + w;
      int r = c * 4 + lrow;
      int jlog = jphys ^ (r & 15);
      __builtin_amdgcn_global_load_lds(
          (const unsigned*)&Wt2[(size_t)r * 256 + kb * 128 + jlog * 8],
          (unsigned*)&Blds[c * 512], 16, 0, 0);
    }
    __syncthreads();
    #pragma unroll
    for (int ks = 0; ks < 4; ++ks) {
      int pc = ((quad + ks * 4) ^ m) * 8;
      short8 af = *(const short8*)&AH[(rt * 16 + m) * 268 + kb * 128
                                      + quad * 8 + ks * 32];
      #pragma unroll
      for (int nt = 0; nt < 4; ++nt) {
        short8 bf = *(const short8*)&Blds[(ch * 64 + nt * 16 + m) * 128 + pc];
        a2[nt] = __builtin_amdgcn_mfma_f32_16x16x32_bf16(af, bf, a2[nt], 0, 0, 0);
      }
    }
  }
  // ---- MLP epilogue: residual from registers, single tokens write
  #pragma unroll
  for (int nt = 0; nt < 4; ++nt) {
    int col = ch * 64 + nt * 16 + m;
    float bv = b2_[col];
    #pragma unroll
    for (int r = 0; r < 4; ++r) {
      int row = row0 + rt * 16 + quad * 4 + r;
      float val = a2[nt][r] + bv + v[nt][r];
      tokens[(size_t)row * DD + col] = val;
      v[nt][r] = val;
    }
  }
  if (ln1g_ == nullptr) {
    // ---- layer-1 tail: decoder-head GEMV (tokens . dWc/dWf + bias) -> hrow
    bool coarse = (rloc < NCc);
    const float* dw = coarse ? dWc_ : dWf_;
    float dwv[4];
    #pragma unroll
    for (int nt = 0; nt < 4; ++nt) dwv[nt] = dw[ch * 64 + nt * 16 + m];
    #pragma unroll
    for (int r = 0; r < 4; ++r) {
      float s = v[0][r] * dwv[0] + v[1][r] * dwv[1]
              + v[2][r] * dwv[2] + v[3][r] * dwv[3];
      #pragma unroll
      for (int o = 1; o < 16; o <<= 1) s += __shfl_xor(s, o);
      if (m == 0) pls[ch][rt * 16 + quad * 4 + r] = s;
    }
    __syncthreads();
    if (m == 0 && ch == 0) {
      float dbv = coarse ? dbc_[0] : dbf_[0];
      #pragma unroll
      for (int r = 0; r < 4; ++r) {
        int lr = rt * 16 + quad * 4 + r;
        hrow[row0 + lr] = pls[0][lr] + pls[1][lr] + dbv;
      }
    }
    return;
  }
  // ---- LN1 stats (layer 0 only)
  #pragma unroll
  for (int r = 0; r < 4; ++r) {
    float s = v[0][r] + v[1][r] + v[2][r] + v[3][r];
    float q = v[0][r] * v[0][r] + v[1][r] * v[1][r]
            + v[2][r] * v[2][r] + v[3][r] * v[3][r];
    #pragma unroll
    for (int o = 1; o < 16; o <<= 1) { s += __shfl_xor(s, o); q += __shfl_xor(q, o); }
    if (m == 0) {
      int lr = rt * 16 + quad * 4 + r;
      pls[ch][lr] = s;
      plq[ch][lr] = q;
    }
  }
  __syncthreads();
  // ---- QKV chunk-0 DMA now (overlaps LN1 apply)
  #pragma unroll
  for (int j = 0; j < 8; ++j) {
    int c = j * 4 + w;
    int r = c * 4 + lrow;
    int jlog = jphys ^ (r & 15);
    __builtin_amdgcn_global_load_lds(
        (const unsigned*)&WtQ[(size_t)r * 128 + jlog * 8],
        (unsigned*)&Blds[c * 512], 16, 0, 0);
  }
  #pragma unroll
  for (int r = 0; r < 4; ++r) {
    int lr = rt * 16 + quad * 4 + r;
    float S = pls[0][lr] + pls[1][lr];
    float Q = plq[0][lr] + plq[1][lr];
    float mean = S * (1.f / 128.f);
    float var = Q * (1.f / 128.f) - mean * mean;
    float rstd = rsqrtf(var + 1e-5f);
    #pragma unroll
    for (int nt = 0; nt < 4; ++nt) {
      int col = ch * 64 + nt * 16 + m;
      Ylds[lr * 136 + col] = f2bf((v[nt][r] - mean) * rstd * ln1g_[col] + ln1b_[col]);
    }
  }
  // ---- next-layer QKV GEMM: 3 chunks of 128 output cols
  for (int c3 = 0; c3 < 3; ++c3) {
    if (c3) {
      __syncthreads();
      #pragma unroll
      for (int j = 0; j < 8; ++j) {
        int c = j * 4 + w;
        int r = c * 4 + lrow;
        int jlog = jphys ^ (r & 15);
        __builtin_amdgcn_global_load_lds(
            (const unsigned*)&WtQ[(size_t)(c3 * 128 + r) * 128 + jlog * 8],
            (unsigned*)&Blds[c * 512], 16, 0, 0);
      }
    }
    __syncthreads();
    f32x4 qa[4] = {zero, zero, zero, zero};
    #pragma unroll
    for (int ks = 0; ks < 4; ++ks) {
      short8 af = *(const short8*)&Ylds[(rt * 16 + m) * 136 + quad * 8 + ks * 32];
      int pc = ((quad + ks * 4) ^ m) * 8;
      #pragma unroll
      for (int nt = 0; nt < 4; ++nt) {
        short8 bf = *(const short8*)&Blds[(ch * 64 + nt * 16 + m) * 128 + pc];
        qa[nt] = __builtin_amdgcn_mfma_f32_16x16x32_bf16(af, bf, qa[nt], 0, 0, 0);
      }
    }
    #pragma unroll
    for (int nt = 0; nt < 4; ++nt) {
      int col = c3 * 128 + ch * 64 + nt * 16 + m;
      #pragma unroll
      for (int r = 0; r < 4; ++r) {
        int row = row0 + rt * 16 + quad * 4 + r;
        qkvb[(size_t)row * 384 + col] = f2bf(qa[nt][r]);
      }
    }
  }
}

// ---------------- layer-0 fused kernel (Wo+LN2+MLP+LN1+QKV)
__global__ __launch_bounds__(256) void k_fused(const short* __restrict__ Opart,
    const float* __restrict__ Lpart, const short* __restrict__ WtO,
    const float* __restrict__ bo_, const float* __restrict__ ln2g_,
    const float* __restrict__ ln2b_, const short* __restrict__ Wt1,
    const float* __restrict__ b1_, const short* __restrict__ Wt2,
    const float* __restrict__ b2_, float* __restrict__ tokens,
    const float* __restrict__ ln1g_, const float* __restrict__ ln1b_,
    const short* __restrict__ WtQ, short* __restrict__ qkvb) {
  fused_body(blockIdx.x * 32, Opart, Lpart, WtO, bo_, ln2g_, ln2b_,
             Wt1, b1_, Wt2, b2_, tokens, ln1g_, ln1b_, WtQ, qkvb,
             nullptr, nullptr, nullptr, nullptr, nullptr);
}

// ---------------- mega3: layer-1 fused (Wo+LN2+MLP+head GEMV) + grid barrier
// + decoder (scatter + bilinear + conv3x3+relu+conv3x3), 256 thr / 4 px each
__global__ __launch_bounds__(256, 2) void k_mega3(const short* __restrict__ Opart,
    const float* __restrict__ Lpart, const short* __restrict__ WtO,
    const float* __restrict__ bo_, const float* __restrict__ ln2g_,
    const float* __restrict__ ln2b_, const short* __restrict__ Wt1,
    const float* __restrict__ b1_, const short* __restrict__ Wt2,
    const float* __restrict__ b2_, float* __restrict__ tokens,
    const float* __restrict__ dWc_, const float* __restrict__ dbc_,
    const float* __restrict__ dWf_, const float* __restrict__ dbf_,
    float* __restrict__ hrow, const float* __restrict__ msort,
    const int* __restrict__ order, const float* __restrict__ fW1,
    const float* __restrict__ fb1, const float* __restrict__ fW2,
    const float* __restrict__ fb2, float* __restrict__ outp,
    int* __restrict__ bars) {
  bar_init(bars);
  fused_body(blockIdx.x * 32, Opart, Lpart, WtO, bo_, ln2g_, ln2b_,
             Wt1, b1_, Wt2, b2_, tokens, nullptr, nullptr, nullptr, nullptr,
             dWc_, dbc_, dWf_, dbf_, hrow);
  grid_barrier(bars, 320);
  if (blockIdx.x < 8) {
    int b = blockIdx.x;
    int t = threadIdx.x;
    __shared__ float cmap[NCc];
    __shared__ float fmap[1024];
    __shared__ float cup[1024];
    __shared__ float hb[2][1024];
    cmap[t] = hrow[b * NTOK + t];
    #pragma unroll
    for (int i = 0; i < 4; ++i) {
      int c = t + 256 * i;
      fmap[order[b * NFf + c]] = hrow[b * NTOK + NCc + c] * msort[b * NFf + c];
    }
    __syncthreads();
    #pragma unroll
    for (int i = 0; i < 4; ++i) {
      int p = t + 256 * i;
      int y = p >> 5, x = p & 31;
      float ys = y * (15.f / 31.f);
      float xs = x * (15.f / 31.f);
      int y0 = (int)floorf(ys); int y1 = min(y0 + 1, 15); float wy = ys - (float)y0;
      int x0 = (int)floorf(xs); int x1 = min(x0 + 1, 15); float wx = xs - (float)x0;
      cup[p] = cmap[y0 * 16 + x0] * (1.f - wy) * (1.f - wx)
             + cmap[y0 * 16 + x1] * (1.f - wy) * wx
             + cmap[y1 * 16 + x0] * wy * (1.f - wx)
             + cmap[y1 * 16 + x1] * wy * wx;
    }
    __syncthreads();
    #pragma unroll
    for (int i = 0; i < 4; ++i) {
      int p = t + 256 * i;
      int y = p >> 5, x = p & 31;
      for (int oc = 0; oc < 2; ++oc) {
        float a = fb1[oc];
        #pragma unroll
        for (int ic = 0; ic < 2; ++ic)
          #pragma unroll
          for (int ky = 0; ky < 3; ++ky)
            #pragma unroll
            for (int kx = 0; kx < 3; ++kx) {
              int yy = y + ky - 1, xx = x + kx - 1;
              float vv = 0.f;
              if (yy >= 0 && yy < 32 && xx >= 0 && xx < 32)
                vv = ic == 0 ? cup[yy * 32 + xx] : fmap[yy * 32 + xx];
              a += vv * fW1[((oc * 2 + ic) * 3 + ky) * 3 + kx];
            }
        hb[oc][p] = fmaxf(a, 0.f);
      }
    }
    __syncthreads();
    #pragma unroll
    for (int i = 0; i < 4; ++i) {
      int p = t + 256 * i;
      int y = p >> 5, x = p & 31;
      float a = fb2[0];
      #pragma unroll
      for (int ic = 0; ic < 2; ++ic)
        #pragma unroll
        for (int ky = 0; ky < 3; ++ky)
          #pragma unroll
          for (int kx = 0; kx < 3; ++kx) {
            int yy = y + ky - 1, xx = x + kx - 1;
            float vv = (yy >= 0 && yy < 32 && xx >= 0 && xx < 32)
                          ? hb[ic][yy * 32 + xx] : 0.f;
            a += vv * fW2[(ic * 3 + ky) * 3 + kx];
          }
      outp[b * 1024 + p] = a;
    }
  }
}

// ---------------- flash attention: split-K (SPLIT=2), fixed-max softmax,
// swizzled Ks, two barriers/stage (implicit wave overlap does the pipelining)
__global__ __launch_bounds__(256) void k_attn4(const short* __restrict__ qkv,
    short* __restrict__ Opart, float* __restrict__ Lpart) {
  __shared__ short Ks[64 * 32];      // [key][d], DMA, chunk swizzle f(k)=(k>>1)&3
  __shared__ short Vt[32 * 74];      // [d][key], stride 74 (free scatter+gather)
  __shared__ short Pl[4][16 * 74];   // per-wave P [q][key]

  int sk = blockIdx.x % SPLIT;
  int qt = (blockIdx.x / SPLIT) % NQT;
  int h  = (blockIdx.x / (SPLIT * NQT)) % HEADS;
  int b  = blockIdx.x / (SPLIT * NQT * HEADS);
  int t = threadIdx.x;
  int lane = t & 63, w = t >> 6;
  int m = lane & 15, quad = lane >> 4;
  int q0 = qt * 64 + w * 16;

  const float scale = 0.17677669529663687f;  // 1/sqrt(32), folded into Q
  short8 qraw = *(const short8*)(qkv + ((size_t)(b * NTOK) + q0 + m) * 384 + h * HD + quad * 8);
  short8 qf;
  #pragma unroll
  for (int j = 0; j < 8; ++j) qf[j] = f2bf(bf2f(qraw[j]) * scale);

  f32x4 zero = {0.f, 0.f, 0.f, 0.f};
  f32x4 Oacc[2] = {zero, zero};
  float psum[4] = {0.f, 0.f, 0.f, 0.f};

  int skey = t >> 2, sdseg = t & 3;  // staging: key 0..63, 8 dims each
  int jlogK = sdseg ^ ((skey >> 1) & 3);
  const short* kstage = qkv + ((size_t)(b * NTOK) + skey) * 384 + 128 + h * HD + jlogK * 8;
  const short* vstage = qkv + ((size_t)(b * NTOK) + skey) * 384 + 256 + h * HD + sdseg * 8;
  int kswz = (quad ^ ((m >> 1) & 3)) * 8;   // read-side physical chunk offset

  for (int s = sk * NSTG; s < sk * NSTG + NSTG; ++s) {
    __syncthreads();
    __builtin_amdgcn_global_load_lds((const unsigned*)(kstage + (size_t)s * 64 * 384),
                                     (unsigned*)&Ks[w * 512], 16, 0, 0);
    short8 vf = *(const short8*)(vstage + (size_t)s * 64 * 384);
    #pragma unroll
    for (int j = 0; j < 8; ++j) Vt[(sdseg * 8 + j) * 74 + skey] = vf[j];
    __syncthreads();

    // S = Q K^T (C-layout: row=4*quad+reg, col=m); Q pre-scaled
    f32x4 sc[4];
    #pragma unroll
    for (int ct = 0; ct < 4; ++ct) {
      short8 kfrag = *(const short8*)&Ks[(ct * 16 + m) * 32 + kswz];
      sc[ct] = __builtin_amdgcn_mfma_f32_16x16x32_bf16(qf, kfrag, zero, 0, 0, 0);
    }
    // fixed-max softmax: p = exp(s); l accumulated from TRUNCATED p (bias-free)
    #pragma unroll
    for (int ct = 0; ct < 4; ++ct)
      #pragma unroll
      for (int r = 0; r < 4; ++r) {
        float p = __expf(sc[ct][r]);
        unsigned u = __builtin_bit_cast(unsigned, p);
        psum[r] += __builtin_bit_cast(float, u & 0xffff0000u);
        Pl[w][(quad * 4 + r) * 74 + ct * 16 + m] = (short)(u >> 16);
      }
    // O += P @ V
    #pragma unroll
    for (int ks = 0; ks < 2; ++ks) {
      short8 pfrag = *(const short8*)&Pl[w][m * 74 + ks * 32 + quad * 8];
      #pragma unroll
      for (int nt = 0; nt < 2; ++nt) {
        short8 vfrag = *(const short8*)&Vt[(nt * 16 + m) * 74 + ks * 32 + quad * 8];
        Oacc[nt] = __builtin_amdgcn_mfma_f32_16x16x32_bf16(pfrag, vfrag, Oacc[nt], 0, 0, 0);
      }
    }
  }
  // single final ladder per row; write partial O (unnormalized) + l
  #pragma unroll
  for (int r = 0; r < 4; ++r) {
    float ssum = psum[r];
    #pragma unroll
    for (int o = 1; o < 16; o <<= 1) ssum += __shfl_xor(ssum, o);
    int qloc = w * 16 + quad * 4 + r;
    #pragma unroll
    for (int nt = 0; nt < 2; ++nt)
      Opart[(size_t)blockIdx.x * 2048 + qloc * 32 + nt * 16 + m] = f2bf(Oacc[nt][r]);
    if (m == 0) Lpart[(size_t)blockIdx.x * 64 + qloc] = ssum;
  }
}

extern "C" void kernel_launch(void* const* d_in, const int* in_sizes, int n_in,
                              void* d_out, int out_size, void* d_ws, size_t ws_size,
                              hipStream_t stream) {
  const float* x    = (const float*)d_in[0];
  const float* Wpc  = (const float*)d_in[1];
  const float* bpc  = (const float*)d_in[2];
  const float* Wpf  = (const float*)d_in[3];
  const float* bpf  = (const float*)d_in[4];
  const float* te   = (const float*)d_in[5];
  const float* ln1g = (const float*)d_in[6];
  const float* ln1b = (const float*)d_in[7];
  const float* Wqkv = (const float*)d_in[8];
  const float* Wo   = (const float*)d_in[9];
  const float* bo   = (const float*)d_in[10];
  const float* ln2g = (const float*)d_in[11];
  const float* ln2b = (const float*)d_in[12];
  const float* W1   = (const float*)d_in[13];
  const float* b1   = (const float*)d_in[14];
  const float* W2   = (const float*)d_in[15];
  const float* b2   = (const float*)d_in[16];
  const float* dWc  = (const float*)d_in[17];
  const float* dbc  = (const float*)d_in[18];
  const float* dWf  = (const float*)d_in[19];
  const float* dbf  = (const float*)d_in[20];
  const float* fW1  = (const float*)d_in[21];
  const float* fb1  = (const float*)d_in[22];
  const float* fW2  = (const float*)d_in[23];
  const float* fb2  = (const float*)d_in[24];

  char* ws = (char*)d_ws;
  float* tokens = (float*)ws;                 ws += 1310720 * 4;   // fp32 [B*N,128]
  float* fineb  = (float*)ws;                 ws += 1048576 * 4;   // fp32 [B*NF,128]
  short* qkvb   = (short*)ws;                 ws += 3932160 * 2;   // bf16 [B*N,384]
  short* Opart  = (short*)ws;                 ws += (size_t)(Bx * HEADS * NQT * SPLIT) * 2048 * 2;
  float* Lpart  = (float*)ws;                 ws += (size_t)(Bx * HEADS * NQT * SPLIT) * 64 * 4;
  short* WtQKV  = (short*)ws;                 ws += 98304 * 2;     // [L][384][128]
  short* WtO    = (short*)ws;                 ws += 32768 * 2;     // [L][128][128]
  short* Wt1    = (short*)ws;                 ws += 65536 * 2;     // [L][256][128]
  short* Wt2    = (short*)ws;                 ws += 65536 * 2;     // [L][128][256]
  float* ebuf   = (float*)ws;                 ws += 8192 * 4;
  float* msort  = (float*)ws;                 ws += 8192 * 4;
  int*   order  = (int*)ws;                   ws += 8192 * 4;
  float* hrow   = (float*)ws;                 ws += 10240 * 4;     // decoder-head scalars
  int*   bars   = (int*)ws;                   ws += 128 * 4;       // grid-barrier slots

  const int M = Bx * NTOK;                    // 10240

  // mega1: prologue + grid-barrier + edge sort
  k_mega1<<<MEGA1_GRID, 256, 0, stream>>>(x, Wpc, bpc, Wpf, bpf, te,
                                          Wqkv, Wo, W1, W2,
                                          WtQKV, WtO, Wt1, Wt2,
                                          ebuf, tokens, fineb, order, msort, bars);
  k_gather_qkv<<<M / 32, 256, 0, stream>>>(tokens, fineb, order, msort, te,
                                           ln1g, ln1b, WtQKV, qkvb);

  // layer 0: attn -> fused[Wo+LN2+MLP+LN1+QKV(l1)]
  k_attn4<<<Bx * HEADS * NQT * SPLIT, 256, 0, stream>>>(qkvb, Opart, Lpart);
  k_fused<<<M / 32, 256, 0, stream>>>(
      Opart, Lpart, WtO, bo, ln2g, ln2b,
      Wt1, b1, Wt2, b2, tokens,
      ln1g + DD, ln1b + DD, WtQKV + 49152, qkvb);

  // layer 1: attn -> mega3[Wo+LN2+MLP+head GEMV + barrier + decoder]
  k_attn4<<<Bx * HEADS * NQT * SPLIT, 256, 0, stream>>>(qkvb, Opart, Lpart);
  k_mega3<<<M / 32, 256, 0, stream>>>(
      Opart, Lpart, WtO + 16384, bo + DD, ln2g + DD, ln2b + DD,
      Wt1 + 32768, b1 + 256, Wt2 + 32768, b2 + DD, tokens,
      dWc, dbc, dWf, dbf, hrow, msort, order,
      fW1, fb1, fW2, fb2, (float*)d_out, bars + 64);
}

// Round 4
// 221.155 us; speedup vs baseline: 1.4451x; 1.4451x over previous
//
#include <hip/hip_runtime.h>
#include <math.h>

#define Bx 8
#define IMG 128
#define DD 128
#define HEADS 4
#define LL 2
#define PCc 8
#define PFf 4
#define HCc 16
#define NCc 256
#define HFf 32
#define NFf 1024
#define NTOK 1280
#define HD 32
#define SPLIT 2          // key-split factor for flash-decode attention
#define NSTG 10          // stages per split = NTOK/64/SPLIT
#define NQT 20           // NTOK/64 query tiles

typedef __attribute__((ext_vector_type(8))) short short8;
typedef __attribute__((ext_vector_type(4))) float f32x4;

__device__ __forceinline__ short f2bf(float f) {
  unsigned u = __builtin_bit_cast(unsigned, f);
  u += 0x7FFF + ((u >> 16) & 1);   // RNE
  return (short)(u >> 16);
}
__device__ __forceinline__ float bf2f(short s) {
  unsigned u = ((unsigned)(unsigned short)s) << 16;
  return __builtin_bit_cast(float, u);
}

// ---------------- batched prologue: [0,1024) prep_w, [1024,1536) sobel,
// [1536,2560) coarse embed (2 tok/block), [2560,6656) fine embed -> fineb
__global__ __launch_bounds__(256) void k_prologue(const float* __restrict__ x,
    const float* __restrict__ Wpc, const float* __restrict__ bpc,
    const float* __restrict__ Wpf, const float* __restrict__ bpf,
    const float* __restrict__ te,
    const float* __restrict__ Wqkv, const float* __restrict__ Wo,
    const float* __restrict__ W1, const float* __restrict__ W2,
    short* __restrict__ WtQKV, short* __restrict__ WtO,
    short* __restrict__ Wt1, short* __restrict__ Wt2,
    float* __restrict__ e, float* __restrict__ tokens,
    float* __restrict__ fineb) {
  int blk = blockIdx.x;
  int t = threadIdx.x;
  if (blk < 1024) {
    // ---- weight prep: transpose + bf16
    int idx = blk * 256 + t;   // 0 .. 262143
    int l = idx / 131072, r = idx % 131072;
    const float* src; short* dst; int N, off;
    if (r < 49152)      { src = Wqkv + l * 49152; dst = WtQKV + l * 49152; N = 384; off = r; }
    else if (r < 65536) { src = Wo + l * 16384;  dst = WtO + l * 16384;  N = 128; off = r - 49152; }
    else if (r < 98304) { src = W1 + l * 32768;  dst = Wt1 + l * 32768;  N = 256; off = r - 65536; }
    else                { src = W2 + l * 32768;  dst = Wt2 + l * 32768;  N = 128; off = r - 98304; }
    int k = off / N, n = off % N;
    int K = (r >= 98304) ? 256 : 128;
    dst[(size_t)n * K + k] = f2bf(src[off]);
  } else if (blk < 1536) {
    // ---- sobel + 4x4 avgpool -> cell energy
    int bt = blk - 1024;
    int b = bt >> 6, tile = bt & 63;
    int ty = tile >> 3, tx = tile & 7;
    int ly = t >> 4, lx = t & 15;
    int py = ty * 16 + ly, px = tx * 16 + lx;
    const float* img = x + (size_t)b * IMG * IMG;
    float v[3][3];
    #pragma unroll
    for (int ky = 0; ky < 3; ++ky)
      #pragma unroll
      for (int kx = 0; kx < 3; ++kx) {
        int yy = py + ky - 1, xx = px + kx - 1;
        v[ky][kx] = (yy >= 0 && yy < IMG && xx >= 0 && xx < IMG)
                        ? img[yy * IMG + xx] : 0.f;
      }
    float gx = -v[0][0] + v[0][2] - 2.f * v[1][0] + 2.f * v[1][2] - v[2][0] + v[2][2];
    float gy = -v[0][0] - 2.f * v[0][1] - v[0][2] + v[2][0] + 2.f * v[2][1] + v[2][2];
    __shared__ float sm[256];
    sm[t] = sqrtf(gx * gx + gy * gy);
    __syncthreads();
    if (t < 16) {
      int cy = t >> 2, cx = t & 3;
      float s = 0.f;
      #pragma unroll
      for (int dy = 0; dy < 4; ++dy)
        #pragma unroll
        for (int dx = 0; dx < 4; ++dx) s += sm[(cy * 4 + dy) * 16 + cx * 4 + dx];
      e[b * NFf + (ty * 4 + cy) * 32 + tx * 4 + cx] = s * (1.f / 16.f);
    }
  } else if (blk < 2560) {
    // ---- coarse patch embed, 2 tokens per block
    int bt = (blk - 1536) * 2 + (t >> 7);    // b*NC + tok
    int b = bt / NCc, tok = bt % NCc;
    int hc = tok / HCc, wc = tok % HCc;
    int half = t >> 7, d = t & 127;
    __shared__ float patch[2][PCc * PCc];
    if (d < PCc * PCc) {
      int pi = d / PCc, pj = d % PCc;
      patch[half][d] = x[(b * IMG + hc * PCc + pi) * IMG + wc * PCc + pj];
    }
    __syncthreads();
    float acc = bpc[d] + te[d];
    #pragma unroll 8
    for (int i = 0; i < PCc * PCc; ++i) acc += patch[half][i] * Wpc[i * DD + d];
    tokens[(size_t)(b * NTOK + tok) * DD + d] = acc;
  } else {
    // ---- fine patch embed, 2 tokens per block -> fineb (unsorted, unmasked)
    int ft = (blk - 2560) * 2 + (t >> 7);    // global fine token 0..8191
    int b = ft >> 10, tloc = ft & 1023;
    int hf = tloc >> 5, wf = tloc & 31;
    int half = t >> 7, d = t & 127;
    __shared__ float patch[2][PFf * PFf];
    if (d < PFf * PFf) {
      int pi = d / PFf, pj = d % PFf;
      patch[half][d] = x[(b * IMG + hf * PFf + pi) * IMG + wf * PFf + pj];
    }
    __syncthreads();
    float acc = bpf[d];
    #pragma unroll
    for (int i = 0; i < PFf * PFf; ++i) acc += patch[half][i] * Wpf[i * DD + d];
    fineb[(size_t)(b * NFf + tloc) * DD + d] = acc;
  }
}

// ---------------- mask at per-image mean -> stable-sort order via ballot scan
__global__ __launch_bounds__(1024) void k_edge_sort(const float* __restrict__ e,
    int* __restrict__ order, float* __restrict__ msort) {
  int b = blockIdx.x;
  int t = threadIdx.x;
  int lane = t & 63, wave = t >> 6;
  float ev = e[b * NFf + t];
  __shared__ float wsum[16];
  __shared__ int wcnt[16];
  float r = ev;
  #pragma unroll
  for (int o = 32; o > 0; o >>= 1) r += __shfl_xor(r, o, 64);
  if (lane == 0) wsum[wave] = r;
  __syncthreads();
  float tot = 0.f;
  #pragma unroll
  for (int i = 0; i < 16; ++i) tot += wsum[i];
  float mean = tot * (1.f / 1024.f);
  int m = (ev > mean) ? 1 : 0;
  unsigned long long bal = __ballot(m);
  if (lane == 0) wcnt[wave] = __popcll(bal);
  __syncthreads();
  int wbase = 0, total = 0;
  #pragma unroll
  for (int i = 0; i < 16; ++i) {
    int c = wcnt[i];
    if (i < wave) wbase += c;
    total += c;
  }
  unsigned long long below = (lane == 63) ? ~0ULL : ((1ULL << (lane + 1)) - 1);
  int incl = __popcll(bal & below);
  int eb = wbase + incl - m;       // edges strictly before t
  int pos = m ? eb : (total + t - eb);
  order[b * NFf + pos] = t;
  msort[b * NFf + pos] = (float)m;
}

// ---------------- gather + LN1 + layer-0 QKV GEMM, 32 rows/block
__global__ __launch_bounds__(256) void k_gather_qkv(float* __restrict__ tokens,
    const float* __restrict__ fineb, const int* __restrict__ order,
    const float* __restrict__ msort, const float* __restrict__ te,
    const float* __restrict__ g, const float* __restrict__ bb,
    const short* __restrict__ WtQ, short* __restrict__ qkvb) {
  __shared__ short Blds[128 * 128];
  __shared__ short Ylds[32 * 136];
  int row0 = blockIdx.x * 32;
  int t = threadIdx.x;
  int lane = t & 63, w = t >> 6;
  int m = lane & 15, quad = lane >> 4;
  int rt = w >> 1, ch = w & 1;
  int lrow = lane >> 4, jphys = lane & 15;
  f32x4 zero = {0.f, 0.f, 0.f, 0.f};

  // ---- issue QKV chunk-0 weight DMA now; drains at the first barrier
  #pragma unroll
  for (int j = 0; j < 8; ++j) {
    int c = j * 4 + w;
    int r = c * 4 + lrow;
    int jlog = jphys ^ (r & 15);
    __builtin_amdgcn_global_load_lds(
        (const unsigned*)&WtQ[(size_t)r * 128 + jlog * 8],
        (unsigned*)&Blds[c * 512], 16, 0, 0);
  }
  // ---- phase A: gather + LN1 -> Ylds (8 rows per wave)
  float2 gg = ((const float2*)g)[lane];
  float2 bv = ((const float2*)bb)[lane];
  #pragma unroll
  for (int rr = 0; rr < 8; ++rr) {
    int lr = w * 8 + rr;
    int row = row0 + lr;
    int b = row / NTOK, rl = row % NTOK;
    float2 v;
    if (rl < NCc) {
      v = ((const float2*)(tokens + (size_t)row * DD))[lane];
    } else {
      int pos = rl - NCc;
      int src = order[b * NFf + pos];
      float mk = msort[b * NFf + pos];
      float2 u = ((const float2*)(fineb + (size_t)(b * NFf + src) * DD))[lane];
      float2 tv = ((const float2*)(te + DD))[lane];
      v.x = u.x * mk + tv.x;
      v.y = u.y * mk + tv.y;
      ((float2*)(tokens + (size_t)row * DD))[lane] = v;
    }
    float s = v.x + v.y;
    #pragma unroll
    for (int o = 32; o > 0; o >>= 1) s += __shfl_xor(s, o, 64);
    float mean = s * (1.f / 128.f);
    float cx = v.x - mean, cy = v.y - mean;
    float q = cx * cx + cy * cy;
    #pragma unroll
    for (int o = 32; o > 0; o >>= 1) q += __shfl_xor(q, o, 64);
    float rstd = rsqrtf(q * (1.f / 128.f) + 1e-5f);
    int p = (int)(unsigned short)f2bf(cx * rstd * gg.x + bv.x)
          | ((int)(unsigned short)f2bf(cy * rstd * gg.y + bv.y) << 16);
    ((int*)Ylds)[lr * 68 + lane] = p;
  }
  // ---- phase B: QKV GEMM, 3 chunks of 128 output cols
  for (int c3 = 0; c3 < 3; ++c3) {
    if (c3) {
      __syncthreads();
      #pragma unroll
      for (int j = 0; j < 8; ++j) {
        int c = j * 4 + w;
        int r = c * 4 + lrow;
        int jlog = jphys ^ (r & 15);
        __builtin_amdgcn_global_load_lds(
            (const unsigned*)&WtQ[(size_t)(c3 * 128 + r) * 128 + jlog * 8],
            (unsigned*)&Blds[c * 512], 16, 0, 0);
      }
    }
    __syncthreads();
    f32x4 qa[4] = {zero, zero, zero, zero};
    #pragma unroll
    for (int ks = 0; ks < 4; ++ks) {
      short8 af = *(const short8*)&Ylds[(rt * 16 + m) * 136 + quad * 8 + ks * 32];
      int pc = ((quad + ks * 4) ^ m) * 8;
      #pragma unroll
      for (int nt = 0; nt < 4; ++nt) {
        short8 bf = *(const short8*)&Blds[(ch * 64 + nt * 16 + m) * 128 + pc];
        qa[nt] = __builtin_amdgcn_mfma_f32_16x16x32_bf16(af, bf, qa[nt], 0, 0, 0);
      }
    }
    #pragma unroll
    for (int nt = 0; nt < 4; ++nt) {
      int col = c3 * 128 + ch * 64 + nt * 16 + m;
      #pragma unroll
      for (int r = 0; r < 4; ++r) {
        int row = row0 + rt * 16 + quad * 4 + r;
        qkvb[(size_t)row * 384 + col] = f2bf(qa[nt][r]);
      }
    }
  }
}

// ---------------- fused transformer tail for one layer, 32 rows/block:
//   1. Wo GEMM (split-K attention combine as A) + residual (register-carried)
//   2. LN2 -> Ylds   3. MLP (h in LDS) + residual -> tokens
//   4a. [layer 0] LN1 -> Ylds, next-layer QKV GEMM -> qkvb
//   4b. [layer 1] decoder-head GEMV (tokens . dWc/dWf + bias) -> hrow
__global__ __launch_bounds__(256) void k_fused(const short* __restrict__ Opart,
    const float* __restrict__ Lpart, const short* __restrict__ WtO,
    const float* __restrict__ bo_, const float* __restrict__ ln2g_,
    const float* __restrict__ ln2b_, const short* __restrict__ Wt1,
    const float* __restrict__ b1_, const short* __restrict__ Wt2,
    const float* __restrict__ b2_, float* __restrict__ tokens,
    const float* __restrict__ ln1g_, const float* __restrict__ ln1b_,
    const short* __restrict__ WtQ, short* __restrict__ qkvb,
    const float* __restrict__ dWc_, const float* __restrict__ dbc_,
    const float* __restrict__ dWf_, const float* __restrict__ dbf_,
    float* __restrict__ hrow) {
  __shared__ short Blds[128 * 128];   // staged weight chunk (Wo / W1 / W2 / WtQ)
  __shared__ short AH[32 * 268];      // aliased: Wo-A (stride 136) then H (stride 268)
  __shared__ short Ylds[32 * 136];    // LN'd activations (LN2 y, later LN1 y)
  __shared__ float pls[2][32], plq[2][32];
  int row0 = blockIdx.x * 32;
  int b = row0 / NTOK;
  int rloc = row0 % NTOK;
  int qt = rloc >> 6, qoff = rloc & 63;   // 0 or 32
  int t = threadIdx.x;
  int lane = t & 63, w = t >> 6;
  int m = lane & 15, quad = lane >> 4;
  int rt = w >> 1, ch = w & 1;
  int lrow = lane >> 4, jphys = lane & 15;
  f32x4 zero = {0.f, 0.f, 0.f, 0.f};

  // ---- Wo B staging (DMA), overlaps A combine below
  #pragma unroll
  for (int j = 0; j < 8; ++j) {
    int c = j * 4 + w;                 // 0..31 (4 rows each)
    int r = c * 4 + lrow;
    int jlog = jphys ^ (r & 15);
    __builtin_amdgcn_global_load_lds(
        (const unsigned*)&WtO[(size_t)r * 128 + jlog * 8],
        (unsigned*)&Blds[c * 512], 16, 0, 0);
  }
  // ---- A staging: combine split-K attention partials, normalize by L
  #pragma unroll
  for (int it = 0; it < 2; ++it) {
    int idx = t + it * 256;            // 512 short8 chunks (32 rows x 16)
    int q = idx >> 4, j = idx & 15;
    int dh = j >> 2, dd = (j & 3) * 8;
    int qg = qoff + q;                 // q within the 64-row attention tile
    size_t pb = ((size_t)(b * HEADS + dh) * NQT + qt) * SPLIT;
    float L = 0.f;
    #pragma unroll
    for (int sk = 0; sk < SPLIT; ++sk) L += Lpart[(pb + sk) * 64 + qg];
    float o[8] = {0, 0, 0, 0, 0, 0, 0, 0};
    #pragma unroll
    for (int sk = 0; sk < SPLIT; ++sk) {
      short8 po = *(const short8*)&Opart[(pb + sk) * 2048 + qg * 32 + dd];
      #pragma unroll
      for (int i = 0; i < 8; ++i) o[i] += bf2f(po[i]);
    }
    float rs = 1.f / L;
    short8 ov;
    #pragma unroll
    for (int i = 0; i < 8; ++i) ov[i] = f2bf(o[i] * rs);
    *(short8*)&AH[q * 136 + j * 8] = ov;
  }
  __syncthreads();
  // ---- Wo GEMM
  f32x4 acc[4] = {zero, zero, zero, zero};
  #pragma unroll
  for (int ks = 0; ks < 4; ++ks) {
    short8 af = *(const short8*)&AH[(rt * 16 + m) * 136 + quad * 8 + ks * 32];
    int pc = ((quad + ks * 4) ^ m) * 8;
    #pragma unroll
    for (int nt = 0; nt < 4; ++nt) {
      short8 bf = *(const short8*)&Blds[(ch * 64 + nt * 16 + m) * 128 + pc];
      acc[nt] = __builtin_amdgcn_mfma_f32_16x16x32_bf16(af, bf, acc[nt], 0, 0, 0);
    }
  }
  // ---- residual (register-carried) + LN2 stats
  float v[4][4];
  #pragma unroll
  for (int nt = 0; nt < 4; ++nt) {
    int col = ch * 64 + nt * 16 + m;
    float bv = bo_[col];
    #pragma unroll
    for (int r = 0; r < 4; ++r) {
      int row = row0 + rt * 16 + quad * 4 + r;
      v[nt][r] = acc[nt][r] + bv + tokens[(size_t)row * DD + col];
    }
  }
  #pragma unroll
  for (int r = 0; r < 4; ++r) {
    float s = v[0][r] + v[1][r] + v[2][r] + v[3][r];
    float q = v[0][r] * v[0][r] + v[1][r] * v[1][r]
            + v[2][r] * v[2][r] + v[3][r] * v[3][r];
    #pragma unroll
    for (int o = 1; o < 16; o <<= 1) { s += __shfl_xor(s, o); q += __shfl_xor(q, o); }
    if (m == 0) {
      int lr = rt * 16 + quad * 4 + r;
      pls[ch][lr] = s;
      plq[ch][lr] = q;
    }
  }
  __syncthreads();   // stats published; all Wo Blds/AH reads drained
  // ---- W1 half-0 DMA now (overlaps LN2 apply)
  #pragma unroll
  for (int j = 0; j < 8; ++j) {
    int c = j * 4 + w;
    int r = c * 4 + lrow;
    int jlog = jphys ^ (r & 15);
    __builtin_amdgcn_global_load_lds(
        (const unsigned*)&Wt1[(size_t)r * 128 + jlog * 8],
        (unsigned*)&Blds[c * 512], 16, 0, 0);
  }
  // ---- LN2 apply -> Ylds
  #pragma unroll
  for (int r = 0; r < 4; ++r) {
    int lr = rt * 16 + quad * 4 + r;
    float S = pls[0][lr] + pls[1][lr];
    float Q = plq[0][lr] + plq[1][lr];
    float mean = S * (1.f / 128.f);
    float var = Q * (1.f / 128.f) - mean * mean;
    float rstd = rsqrtf(var + 1e-5f);
    #pragma unroll
    for (int nt = 0; nt < 4; ++nt) {
      int col = ch * 64 + nt * 16 + m;
      Ylds[lr * 136 + col] = f2bf((v[nt][r] - mean) * rstd * ln2g_[col] + ln2b_[col]);
    }
  }
  // ---- MLP: h = gelu(y @ W1 + b1) -> AH (stride 268)
  for (int hh = 0; hh < 2; ++hh) {
    if (hh) {
      __syncthreads();                 // half-0 Blds reads drained
      #pragma unroll
      for (int j = 0; j < 8; ++j) {
        int c = j * 4 + w;
        int r = c * 4 + lrow;
        int jlog = jphys ^ (r & 15);
        __builtin_amdgcn_global_load_lds(
            (const unsigned*)&Wt1[(size_t)(128 + r) * 128 + jlog * 8],
            (unsigned*)&Blds[c * 512], 16, 0, 0);
      }
    }
    __syncthreads();   // DMA drained (+ Ylds published on hh=0)
    f32x4 ha[4] = {zero, zero, zero, zero};
    #pragma unroll
    for (int ks = 0; ks < 4; ++ks) {
      short8 af = *(const short8*)&Ylds[(rt * 16 + m) * 136 + quad * 8 + ks * 32];
      int pc = ((quad + ks * 4) ^ m) * 8;
      #pragma unroll
      for (int nt = 0; nt < 4; ++nt) {
        short8 bf = *(const short8*)&Blds[(ch * 64 + nt * 16 + m) * 128 + pc];
        ha[nt] = __builtin_amdgcn_mfma_f32_16x16x32_bf16(af, bf, ha[nt], 0, 0, 0);
      }
    }
    #pragma unroll
    for (int nt = 0; nt < 4; ++nt) {
      int n = hh * 128 + ch * 64 + nt * 16 + m;
      float bv = b1_[n];
      #pragma unroll
      for (int r = 0; r < 4; ++r) {
        float vv = ha[nt][r] + bv;
        vv = 0.5f * vv * (1.f + erff(vv * 0.70710678118654752f));
        AH[(rt * 16 + quad * 4 + r) * 268 + n] = f2bf(vv);
      }
    }
  }
  // ---- W2: K=256 in two chunks (chunk kb == H half kb)
  f32x4 a2[4] = {zero, zero, zero, zero};
  for (int kb = 0; kb < 2; ++kb) {
    __syncthreads();                   // Blds reads drained + H published
    #pragma unroll
    for (int j = 0; j < 8; ++j) {
      int c = j * 4 + w;
      int r = c * 4 + lrow;
      int jlog = jphys ^ (r & 15);
      __builtin_amdgcn_global_load_lds(
          (const unsigned*)&Wt2[(size_t)r * 256 + kb * 128 + jlog * 8],
          (unsigned*)&Blds[c * 512], 16, 0, 0);
    }
    __syncthreads();
    #pragma unroll
    for (int ks = 0; ks < 4; ++ks) {
      int pc = ((quad + ks * 4) ^ m) * 8;
      short8 af = *(const short8*)&AH[(rt * 16 + m) * 268 + kb * 128
                                      + quad * 8 + ks * 32];
      #pragma unroll
      for (int nt = 0; nt < 4; ++nt) {
        short8 bf = *(const short8*)&Blds[(ch * 64 + nt * 16 + m) * 128 + pc];
        a2[nt] = __builtin_amdgcn_mfma_f32_16x16x32_bf16(af, bf, a2[nt], 0, 0, 0);
      }
    }
  }
  // ---- MLP epilogue: residual from registers, single tokens write
  #pragma unroll
  for (int nt = 0; nt < 4; ++nt) {
    int col = ch * 64 + nt * 16 + m;
    float bv = b2_[col];
    #pragma unroll
    for (int r = 0; r < 4; ++r) {
      int row = row0 + rt * 16 + quad * 4 + r;
      float val = a2[nt][r] + bv + v[nt][r];
      tokens[(size_t)row * DD + col] = val;
      v[nt][r] = val;
    }
  }
  if (ln1g_ == nullptr) {
    // ---- layer-1 tail: decoder-head GEMV fused (tokens . dWc/dWf + bias)
    bool coarse = (rloc < NCc);        // block-uniform (NC multiple of 32)
    const float* dw = coarse ? dWc_ : dWf_;
    float dwv[4];
    #pragma unroll
    for (int nt = 0; nt < 4; ++nt) dwv[nt] = dw[ch * 64 + nt * 16 + m];
    #pragma unroll
    for (int r = 0; r < 4; ++r) {
      float s = v[0][r] * dwv[0] + v[1][r] * dwv[1]
              + v[2][r] * dwv[2] + v[3][r] * dwv[3];
      #pragma unroll
      for (int o = 1; o < 16; o <<= 1) s += __shfl_xor(s, o);
      if (m == 0) pls[ch][rt * 16 + quad * 4 + r] = s;
    }
    __syncthreads();
    if (m == 0 && ch == 0) {
      float dbv = coarse ? dbc_[0] : dbf_[0];
      #pragma unroll
      for (int r = 0; r < 4; ++r) {
        int lr = rt * 16 + quad * 4 + r;
        hrow[row0 + lr] = pls[0][lr] + pls[1][lr] + dbv;
      }
    }
    return;
  }
  // ---- LN1 stats (layer 0 only)
  #pragma unroll
  for (int r = 0; r < 4; ++r) {
    float s = v[0][r] + v[1][r] + v[2][r] + v[3][r];
    float q = v[0][r] * v[0][r] + v[1][r] * v[1][r]
            + v[2][r] * v[2][r] + v[3][r] * v[3][r];
    #pragma unroll
    for (int o = 1; o < 16; o <<= 1) { s += __shfl_xor(s, o); q += __shfl_xor(q, o); }
    if (m == 0) {
      int lr = rt * 16 + quad * 4 + r;
      pls[ch][lr] = s;
      plq[ch][lr] = q;
    }
  }
  __syncthreads();   // stats published + W2 Blds reads drained
  // ---- QKV chunk-0 DMA now (overlaps LN1 apply)
  #pragma unroll
  for (int j = 0; j < 8; ++j) {
    int c = j * 4 + w;
    int r = c * 4 + lrow;
    int jlog = jphys ^ (r & 15);
    __builtin_amdgcn_global_load_lds(
        (const unsigned*)&WtQ[(size_t)r * 128 + jlog * 8],
        (unsigned*)&Blds[c * 512], 16, 0, 0);
  }
  #pragma unroll
  for (int r = 0; r < 4; ++r) {
    int lr = rt * 16 + quad * 4 + r;
    float S = pls[0][lr] + pls[1][lr];
    float Q = plq[0][lr] + plq[1][lr];
    float mean = S * (1.f / 128.f);
    float var = Q * (1.f / 128.f) - mean * mean;
    float rstd = rsqrtf(var + 1e-5f);
    #pragma unroll
    for (int nt = 0; nt < 4; ++nt) {
      int col = ch * 64 + nt * 16 + m;
      Ylds[lr * 136 + col] = f2bf((v[nt][r] - mean) * rstd * ln1g_[col] + ln1b_[col]);
    }
  }
  // ---- next-layer QKV GEMM: 3 chunks of 128 output cols
  for (int c3 = 0; c3 < 3; ++c3) {
    if (c3) {
      __syncthreads();
      #pragma unroll
      for (int j = 0; j < 8; ++j) {
        int c = j * 4 + w;
        int r = c * 4 + lrow;
        int jlog = jphys ^ (r & 15);
        __builtin_amdgcn_global_load_lds(
            (const unsigned*)&WtQ[(size_t)(c3 * 128 + r) * 128 + jlog * 8],
            (unsigned*)&Blds[c * 512], 16, 0, 0);
      }
    }
    __syncthreads();   // DMA drained (+ Ylds published on c3=0)
    f32x4 qa[4] = {zero, zero, zero, zero};
    #pragma unroll
    for (int ks = 0; ks < 4; ++ks) {
      short8 af = *(const short8*)&Ylds[(rt * 16 + m) * 136 + quad * 8 + ks * 32];
      int pc = ((quad + ks * 4) ^ m) * 8;
      #pragma unroll
      for (int nt = 0; nt < 4; ++nt) {
        short8 bf = *(const short8*)&Blds[(ch * 64 + nt * 16 + m) * 128 + pc];
        qa[nt] = __builtin_amdgcn_mfma_f32_16x16x32_bf16(af, bf, qa[nt], 0, 0, 0);
      }
    }
    #pragma unroll
    for (int nt = 0; nt < 4; ++nt) {
      int col = c3 * 128 + ch * 64 + nt * 16 + m;
      #pragma unroll
      for (int r = 0; r < 4; ++r) {
        int row = row0 + rt * 16 + quad * 4 + r;
        qkvb[(size_t)row * 384 + col] = f2bf(qa[nt][r]);
      }
    }
  }
}

// ---------------- flash attention: split-K (SPLIT=2), fixed-max softmax,
// swizzled Ks, two barriers/stage (implicit wave overlap does the pipelining)
__global__ __launch_bounds__(256) void k_attn4(const short* __restrict__ qkv,
    short* __restrict__ Opart, float* __restrict__ Lpart) {
  __shared__ short Ks[64 * 32];      // [key][d], DMA, chunk swizzle f(k)=(k>>1)&3
  __shared__ short Vt[32 * 74];      // [d][key], stride 74 (free scatter+gather)
  __shared__ short Pl[4][16 * 74];   // per-wave P [q][key]

  int sk = blockIdx.x % SPLIT;
  int qt = (blockIdx.x / SPLIT) % NQT;
  int h  = (blockIdx.x / (SPLIT * NQT)) % HEADS;
  int b  = blockIdx.x / (SPLIT * NQT * HEADS);
  int t = threadIdx.x;
  int lane = t & 63, w = t >> 6;
  int m = lane & 15, quad = lane >> 4;
  int q0 = qt * 64 + w * 16;

  const float scale = 0.17677669529663687f;  // 1/sqrt(32), folded into Q
  short8 qraw = *(const short8*)(qkv + ((size_t)(b * NTOK) + q0 + m) * 384 + h * HD + quad * 8);
  short8 qf;
  #pragma unroll
  for (int j = 0; j < 8; ++j) qf[j] = f2bf(bf2f(qraw[j]) * scale);

  f32x4 zero = {0.f, 0.f, 0.f, 0.f};
  f32x4 Oacc[2] = {zero, zero};
  float psum[4] = {0.f, 0.f, 0.f, 0.f};

  int skey = t >> 2, sdseg = t & 3;  // staging: key 0..63, 8 dims each
  int jlogK = sdseg ^ ((skey >> 1) & 3);
  const short* kstage = qkv + ((size_t)(b * NTOK) + skey) * 384 + 128 + h * HD + jlogK * 8;
  const short* vstage = qkv + ((size_t)(b * NTOK) + skey) * 384 + 256 + h * HD + sdseg * 8;
  int kswz = (quad ^ ((m >> 1) & 3)) * 8;   // read-side physical chunk offset

  for (int s = sk * NSTG; s < sk * NSTG + NSTG; ++s) {
    __syncthreads();
    __builtin_amdgcn_global_load_lds((const unsigned*)(kstage + (size_t)s * 64 * 384),
                                     (unsigned*)&Ks[w * 512], 16, 0, 0);
    short8 vf = *(const short8*)(vstage + (size_t)s * 64 * 384);
    #pragma unroll
    for (int j = 0; j < 8; ++j) Vt[(sdseg * 8 + j) * 74 + skey] = vf[j];
    __syncthreads();

    // S = Q K^T (C-layout: row=4*quad+reg, col=m); Q pre-scaled
    f32x4 sc[4];
    #pragma unroll
    for (int ct = 0; ct < 4; ++ct) {
      short8 kfrag = *(const short8*)&Ks[(ct * 16 + m) * 32 + kswz];
      sc[ct] = __builtin_amdgcn_mfma_f32_16x16x32_bf16(qf, kfrag, zero, 0, 0, 0);
    }
    // fixed-max softmax: p = exp(s); l accumulated from TRUNCATED p (bias-free)
    #pragma unroll
    for (int ct = 0; ct < 4; ++ct)
      #pragma unroll
      for (int r = 0; r < 4; ++r) {
        float p = __expf(sc[ct][r]);
        unsigned u = __builtin_bit_cast(unsigned, p);
        psum[r] += __builtin_bit_cast(float, u & 0xffff0000u);
        Pl[w][(quad * 4 + r) * 74 + ct * 16 + m] = (short)(u >> 16);
      }
    // O += P @ V
    #pragma unroll
    for (int ks = 0; ks < 2; ++ks) {
      short8 pfrag = *(const short8*)&Pl[w][m * 74 + ks * 32 + quad * 8];
      #pragma unroll
      for (int nt = 0; nt < 2; ++nt) {
        short8 vfrag = *(const short8*)&Vt[(nt * 16 + m) * 74 + ks * 32 + quad * 8];
        Oacc[nt] = __builtin_amdgcn_mfma_f32_16x16x32_bf16(pfrag, vfrag, Oacc[nt], 0, 0, 0);
      }
    }
  }
  // single final ladder per row; write partial O (unnormalized) + l
  #pragma unroll
  for (int r = 0; r < 4; ++r) {
    float ssum = psum[r];
    #pragma unroll
    for (int o = 1; o < 16; o <<= 1) ssum += __shfl_xor(ssum, o);
    int qloc = w * 16 + quad * 4 + r;
    #pragma unroll
    for (int nt = 0; nt < 2; ++nt)
      Opart[(size_t)blockIdx.x * 2048 + qloc * 32 + nt * 16 + m] = f2bf(Oacc[nt][r]);
    if (m == 0) Lpart[(size_t)blockIdx.x * 64 + qloc] = ssum;
  }
}

// ---------------- fused decoder: reads precomputed head scalars (hrow),
// scatter + bilinear + conv3x3+relu+conv3x3 — one block per image
__global__ __launch_bounds__(1024) void k_decoder(const float* __restrict__ hrow,
    const float* __restrict__ msort, const int* __restrict__ order,
    const float* __restrict__ fW1, const float* __restrict__ fb1,
    const float* __restrict__ fW2, const float* __restrict__ fb2,
    float* __restrict__ outp) {
  int b = blockIdx.x;
  int t = threadIdx.x;
  __shared__ float cmap[NCc];
  __shared__ float fmap[1024];
  __shared__ float cup[1024];
  __shared__ float hb[2][1024];
  fmap[order[b * NFf + t]] = hrow[b * NTOK + NCc + t] * msort[b * NFf + t];
  if (t < NCc) cmap[t] = hrow[b * NTOK + t];
  __syncthreads();
  int y = t >> 5, x = t & 31;
  {
    float ys = y * (15.f / 31.f);
    float xs = x * (15.f / 31.f);
    int y0 = (int)floorf(ys); int y1 = min(y0 + 1, 15); float wy = ys - (float)y0;
    int x0 = (int)floorf(xs); int x1 = min(x0 + 1, 15); float wx = xs - (float)x0;
    cup[t] = cmap[y0 * 16 + x0] * (1.f - wy) * (1.f - wx)
           + cmap[y0 * 16 + x1] * (1.f - wy) * wx
           + cmap[y1 * 16 + x0] * wy * (1.f - wx)
           + cmap[y1 * 16 + x1] * wy * wx;
  }
  __syncthreads();
  for (int oc = 0; oc < 2; ++oc) {
    float a = fb1[oc];
    #pragma unroll
    for (int ic = 0; ic < 2; ++ic)
      #pragma unroll
      for (int ky = 0; ky < 3; ++ky)
        #pragma unroll
        for (int kx = 0; kx < 3; ++kx) {
          int yy = y + ky - 1, xx = x + kx - 1;
          float v = 0.f;
          if (yy >= 0 && yy < 32 && xx >= 0 && xx < 32)
            v = ic == 0 ? cup[yy * 32 + xx] : fmap[yy * 32 + xx];
          a += v * fW1[((oc * 2 + ic) * 3 + ky) * 3 + kx];
        }
    hb[oc][t] = fmaxf(a, 0.f);
  }
  __syncthreads();
  float a = fb2[0];
  #pragma unroll
  for (int ic = 0; ic < 2; ++ic)
    #pragma unroll
    for (int ky = 0; ky < 3; ++ky)
      #pragma unroll
      for (int kx = 0; kx < 3; ++kx) {
        int yy = y + ky - 1, xx = x + kx - 1;
        float v = (yy >= 0 && yy < 32 && xx >= 0 && xx < 32)
                      ? hb[ic][yy * 32 + xx] : 0.f;
        a += v * fW2[(ic * 3 + ky) * 3 + kx];
      }
  outp[b * 1024 + t] = a;
}

extern "C" void kernel_launch(void* const* d_in, const int* in_sizes, int n_in,
                              void* d_out, int out_size, void* d_ws, size_t ws_size,
                              hipStream_t stream) {
  const float* x    = (const float*)d_in[0];
  const float* Wpc  = (const float*)d_in[1];
  const float* bpc  = (const float*)d_in[2];
  const float* Wpf  = (const float*)d_in[3];
  const float* bpf  = (const float*)d_in[4];
  const float* te   = (const float*)d_in[5];
  const float* ln1g = (const float*)d_in[6];
  const float* ln1b = (const float*)d_in[7];
  const float* Wqkv = (const float*)d_in[8];
  const float* Wo   = (const float*)d_in[9];
  const float* bo   = (const float*)d_in[10];
  const float* ln2g = (const float*)d_in[11];
  const float* ln2b = (const float*)d_in[12];
  const float* W1   = (const float*)d_in[13];
  const float* b1   = (const float*)d_in[14];
  const float* W2   = (const float*)d_in[15];
  const float* b2   = (const float*)d_in[16];
  const float* dWc  = (const float*)d_in[17];
  const float* dbc  = (const float*)d_in[18];
  const float* dWf  = (const float*)d_in[19];
  const float* dbf  = (const float*)d_in[20];
  const float* fW1  = (const float*)d_in[21];
  const float* fb1  = (const float*)d_in[22];
  const float* fW2  = (const float*)d_in[23];
  const float* fb2  = (const float*)d_in[24];

  char* ws = (char*)d_ws;
  float* tokens = (float*)ws;                 ws += 1310720 * 4;   // fp32 [B*N,128]
  float* fineb  = (float*)ws;                 ws += 1048576 * 4;   // fp32 [B*NF,128]
  short* qkvb   = (short*)ws;                 ws += 3932160 * 2;   // bf16 [B*N,384]
  short* Opart  = (short*)ws;                 ws += (size_t)(Bx * HEADS * NQT * SPLIT) * 2048 * 2;
  float* Lpart  = (float*)ws;                 ws += (size_t)(Bx * HEADS * NQT * SPLIT) * 64 * 4;
  short* WtQKV  = (short*)ws;                 ws += 98304 * 2;     // [L][384][128]
  short* WtO    = (short*)ws;                 ws += 32768 * 2;     // [L][128][128]
  short* Wt1    = (short*)ws;                 ws += 65536 * 2;     // [L][256][128]
  short* Wt2    = (short*)ws;                 ws += 65536 * 2;     // [L][128][256]
  float* ebuf   = (float*)ws;                 ws += 8192 * 4;
  float* msort  = (float*)ws;                 ws += 8192 * 4;
  int*   order  = (int*)ws;                   ws += 8192 * 4;
  float* hrow   = (float*)ws;                 ws += 10240 * 4;     // decoder-head scalars

  const int M = Bx * NTOK;                    // 10240

  k_prologue<<<6656, 256, 0, stream>>>(x, Wpc, bpc, Wpf, bpf, te, Wqkv, Wo, W1, W2,
                                       WtQKV, WtO, Wt1, Wt2, ebuf, tokens, fineb);
  k_edge_sort<<<Bx, 1024, 0, stream>>>(ebuf, order, msort);
  k_gather_qkv<<<M / 32, 256, 0, stream>>>(tokens, fineb, order, msort, te,
                                           ln1g, ln1b, WtQKV, qkvb);

  // layer 0: attn -> fused[Wo+LN2+MLP+LN1+QKV(l1)]
  k_attn4<<<Bx * HEADS * NQT * SPLIT, 256, 0, stream>>>(qkvb, Opart, Lpart);
  k_fused<<<M / 32, 256, 0, stream>>>(
      Opart, Lpart, WtO, bo, ln2g, ln2b,
      Wt1, b1, Wt2, b2, tokens,
      ln1g + DD, ln1b + DD, WtQKV + 49152, qkvb,
      nullptr, nullptr, nullptr, nullptr, nullptr);

  // layer 1: attn -> fused[Wo+LN2+MLP+decoder-head]
  k_attn4<<<Bx * HEADS * NQT * SPLIT, 256, 0, stream>>>(qkvb, Opart, Lpart);
  k_fused<<<M / 32, 256, 0, stream>>>(
      Opart, Lpart, WtO + 16384, bo + DD, ln2g + DD, ln2b + DD,
      Wt1 + 32768, b1 + 256, Wt2 + 32768, b2 + DD, tokens,
      nullptr, nullptr, nullptr, nullptr,
      dWc, dbc, dWf, dbf, hrow);

  k_decoder<<<Bx, 1024, 0, stream>>>(hrow, msort, order,
                                     fW1, fb1, fW2, fb2, (float*)d_out);
}

// Round 5
// 218.434 us; speedup vs baseline: 1.4631x; 1.0125x over previous
//
#include <hip/hip_runtime.h>
#include <math.h>

#define Bx 8
#define IMG 128
#define DD 128
#define HEADS 4
#define LL 2
#define PCc 8
#define PFf 4
#define HCc 16
#define NCc 256
#define HFf 32
#define NFf 1024
#define NTOK 1280
#define HD 32
#define SPLIT 2          // key-split factor for flash-decode attention
#define NSTG 10          // stages per split = NTOK/64/SPLIT
#define NQT 20           // NTOK/64 query tiles

typedef __attribute__((ext_vector_type(8))) short short8;
typedef __attribute__((ext_vector_type(4))) float f32x4;

__device__ __forceinline__ short f2bf(float f) {
  unsigned u = __builtin_bit_cast(unsigned, f);
  u += 0x7FFF + ((u >> 16) & 1);   // RNE
  return (short)(u >> 16);
}
__device__ __forceinline__ float bf2f(short s) {
  unsigned u = ((unsigned)(unsigned short)s) << 16;
  return __builtin_bit_cast(float, u);
}

// ---------------- batched prologue: [0,1024) prep_w, [1024,1536) sobel,
// [1536,2560) coarse embed (2 tok/block), [2560,6656) fine embed -> fineb
__global__ __launch_bounds__(256) void k_prologue(const float* __restrict__ x,
    const float* __restrict__ Wpc, const float* __restrict__ bpc,
    const float* __restrict__ Wpf, const float* __restrict__ bpf,
    const float* __restrict__ te,
    const float* __restrict__ Wqkv, const float* __restrict__ Wo,
    const float* __restrict__ W1, const float* __restrict__ W2,
    short* __restrict__ WtQKV, short* __restrict__ WtO,
    short* __restrict__ Wt1, short* __restrict__ Wt2,
    float* __restrict__ e, float* __restrict__ tokens,
    float* __restrict__ fineb) {
  int blk = blockIdx.x;
  int t = threadIdx.x;
  if (blk < 1024) {
    // ---- weight prep: transpose + bf16
    int idx = blk * 256 + t;   // 0 .. 262143
    int l = idx / 131072, r = idx % 131072;
    const float* src; short* dst; int N, off;
    if (r < 49152)      { src = Wqkv + l * 49152; dst = WtQKV + l * 49152; N = 384; off = r; }
    else if (r < 65536) { src = Wo + l * 16384;  dst = WtO + l * 16384;  N = 128; off = r - 49152; }
    else if (r < 98304) { src = W1 + l * 32768;  dst = Wt1 + l * 32768;  N = 256; off = r - 65536; }
    else                { src = W2 + l * 32768;  dst = Wt2 + l * 32768;  N = 128; off = r - 98304; }
    int k = off / N, n = off % N;
    int K = (r >= 98304) ? 256 : 128;
    dst[(size_t)n * K + k] = f2bf(src[off]);
  } else if (blk < 1536) {
    // ---- sobel + 4x4 avgpool -> cell energy
    int bt = blk - 1024;
    int b = bt >> 6, tile = bt & 63;
    int ty = tile >> 3, tx = tile & 7;
    int ly = t >> 4, lx = t & 15;
    int py = ty * 16 + ly, px = tx * 16 + lx;
    const float* img = x + (size_t)b * IMG * IMG;
    float v[3][3];
    #pragma unroll
    for (int ky = 0; ky < 3; ++ky)
      #pragma unroll
      for (int kx = 0; kx < 3; ++kx) {
        int yy = py + ky - 1, xx = px + kx - 1;
        v[ky][kx] = (yy >= 0 && yy < IMG && xx >= 0 && xx < IMG)
                        ? img[yy * IMG + xx] : 0.f;
      }
    float gx = -v[0][0] + v[0][2] - 2.f * v[1][0] + 2.f * v[1][2] - v[2][0] + v[2][2];
    float gy = -v[0][0] - 2.f * v[0][1] - v[0][2] + v[2][0] + 2.f * v[2][1] + v[2][2];
    __shared__ float sm[256];
    sm[t] = sqrtf(gx * gx + gy * gy);
    __syncthreads();
    if (t < 16) {
      int cy = t >> 2, cx = t & 3;
      float s = 0.f;
      #pragma unroll
      for (int dy = 0; dy < 4; ++dy)
        #pragma unroll
        for (int dx = 0; dx < 4; ++dx) s += sm[(cy * 4 + dy) * 16 + cx * 4 + dx];
      e[b * NFf + (ty * 4 + cy) * 32 + tx * 4 + cx] = s * (1.f / 16.f);
    }
  } else if (blk < 2560) {
    // ---- coarse patch embed, 2 tokens per block
    int bt = (blk - 1536) * 2 + (t >> 7);    // b*NC + tok
    int b = bt / NCc, tok = bt % NCc;
    int hc = tok / HCc, wc = tok % HCc;
    int half = t >> 7, d = t & 127;
    __shared__ float patch[2][PCc * PCc];
    if (d < PCc * PCc) {
      int pi = d / PCc, pj = d % PCc;
      patch[half][d] = x[(b * IMG + hc * PCc + pi) * IMG + wc * PCc + pj];
    }
    __syncthreads();
    float acc = bpc[d] + te[d];
    #pragma unroll 8
    for (int i = 0; i < PCc * PCc; ++i) acc += patch[half][i] * Wpc[i * DD + d];
    tokens[(size_t)(b * NTOK + tok) * DD + d] = acc;
  } else {
    // ---- fine patch embed, 2 tokens per block -> fineb (unsorted, unmasked)
    int ft = (blk - 2560) * 2 + (t >> 7);    // global fine token 0..8191
    int b = ft >> 10, tloc = ft & 1023;
    int hf = tloc >> 5, wf = tloc & 31;
    int half = t >> 7, d = t & 127;
    __shared__ float patch[2][PFf * PFf];
    if (d < PFf * PFf) {
      int pi = d / PFf, pj = d % PFf;
      patch[half][d] = x[(b * IMG + hf * PFf + pi) * IMG + wf * PFf + pj];
    }
    __syncthreads();
    float acc = bpf[d];
    #pragma unroll
    for (int i = 0; i < PFf * PFf; ++i) acc += patch[half][i] * Wpf[i * DD + d];
    fineb[(size_t)(b * NFf + tloc) * DD + d] = acc;
  }
}

// ---------------- mask at per-image mean -> stable-sort order via ballot scan
__global__ __launch_bounds__(1024) void k_edge_sort(const float* __restrict__ e,
    int* __restrict__ order, float* __restrict__ msort) {
  int b = blockIdx.x;
  int t = threadIdx.x;
  int lane = t & 63, wave = t >> 6;
  float ev = e[b * NFf + t];
  __shared__ float wsum[16];
  __shared__ int wcnt[16];
  float r = ev;
  #pragma unroll
  for (int o = 32; o > 0; o >>= 1) r += __shfl_xor(r, o, 64);
  if (lane == 0) wsum[wave] = r;
  __syncthreads();
  float tot = 0.f;
  #pragma unroll
  for (int i = 0; i < 16; ++i) tot += wsum[i];
  float mean = tot * (1.f / 1024.f);
  int m = (ev > mean) ? 1 : 0;
  unsigned long long bal = __ballot(m);
  if (lane == 0) wcnt[wave] = __popcll(bal);
  __syncthreads();
  int wbase = 0, total = 0;
  #pragma unroll
  for (int i = 0; i < 16; ++i) {
    int c = wcnt[i];
    if (i < wave) wbase += c;
    total += c;
  }
  unsigned long long below = (lane == 63) ? ~0ULL : ((1ULL << (lane + 1)) - 1);
  int incl = __popcll(bal & below);
  int eb = wbase + incl - m;       // edges strictly before t
  int pos = m ? eb : (total + t - eb);
  order[b * NFf + pos] = t;
  msort[b * NFf + pos] = (float)m;
}

// ---------------- gather + LN1 + layer-0 QKV GEMM, 32 rows/block
__global__ __launch_bounds__(256) void k_gather_qkv(float* __restrict__ tokens,
    const float* __restrict__ fineb, const int* __restrict__ order,
    const float* __restrict__ msort, const float* __restrict__ te,
    const float* __restrict__ g, const float* __restrict__ bb,
    const short* __restrict__ WtQ, short* __restrict__ qkvb) {
  __shared__ short Blds[128 * 128];
  __shared__ short Ylds[32 * 136];
  int row0 = blockIdx.x * 32;
  int t = threadIdx.x;
  int lane = t & 63, w = t >> 6;
  int m = lane & 15, quad = lane >> 4;
  int rt = w >> 1, ch = w & 1;
  int lrow = lane >> 4, jphys = lane & 15;
  f32x4 zero = {0.f, 0.f, 0.f, 0.f};

  // ---- issue QKV chunk-0 weight DMA now; drains at the first barrier
  #pragma unroll
  for (int j = 0; j < 8; ++j) {
    int c = j * 4 + w;
    int r = c * 4 + lrow;
    int jlog = jphys ^ (r & 15);
    __builtin_amdgcn_global_load_lds(
        (const unsigned*)&WtQ[(size_t)r * 128 + jlog * 8],
        (unsigned*)&Blds[c * 512], 16, 0, 0);
  }
  // ---- phase A: gather + LN1 -> Ylds (8 rows per wave)
  float2 gg = ((const float2*)g)[lane];
  float2 bv = ((const float2*)bb)[lane];
  #pragma unroll
  for (int rr = 0; rr < 8; ++rr) {
    int lr = w * 8 + rr;
    int row = row0 + lr;
    int b = row / NTOK, rl = row % NTOK;
    float2 v;
    if (rl < NCc) {
      v = ((const float2*)(tokens + (size_t)row * DD))[lane];
    } else {
      int pos = rl - NCc;
      int src = order[b * NFf + pos];
      float mk = msort[b * NFf + pos];
      float2 u = ((const float2*)(fineb + (size_t)(b * NFf + src) * DD))[lane];
      float2 tv = ((const float2*)(te + DD))[lane];
      v.x = u.x * mk + tv.x;
      v.y = u.y * mk + tv.y;
      ((float2*)(tokens + (size_t)row * DD))[lane] = v;
    }
    float s = v.x + v.y;
    #pragma unroll
    for (int o = 32; o > 0; o >>= 1) s += __shfl_xor(s, o, 64);
    float mean = s * (1.f / 128.f);
    float cx = v.x - mean, cy = v.y - mean;
    float q = cx * cx + cy * cy;
    #pragma unroll
    for (int o = 32; o > 0; o >>= 1) q += __shfl_xor(q, o, 64);
    float rstd = rsqrtf(q * (1.f / 128.f) + 1e-5f);
    int p = (int)(unsigned short)f2bf(cx * rstd * gg.x + bv.x)
          | ((int)(unsigned short)f2bf(cy * rstd * gg.y + bv.y) << 16);
    ((int*)Ylds)[lr * 68 + lane] = p;
  }
  // ---- phase B: QKV GEMM, 3 chunks of 128 output cols
  for (int c3 = 0; c3 < 3; ++c3) {
    if (c3) {
      __syncthreads();
      #pragma unroll
      for (int j = 0; j < 8; ++j) {
        int c = j * 4 + w;
        int r = c * 4 + lrow;
        int jlog = jphys ^ (r & 15);
        __builtin_amdgcn_global_load_lds(
            (const unsigned*)&WtQ[(size_t)(c3 * 128 + r) * 128 + jlog * 8],
            (unsigned*)&Blds[c * 512], 16, 0, 0);
      }
    }
    __syncthreads();
    f32x4 qa[4] = {zero, zero, zero, zero};
    #pragma unroll
    for (int ks = 0; ks < 4; ++ks) {
      short8 af = *(const short8*)&Ylds[(rt * 16 + m) * 136 + quad * 8 + ks * 32];
      int pc = ((quad + ks * 4) ^ m) * 8;
      #pragma unroll
      for (int nt = 0; nt < 4; ++nt) {
        short8 bf = *(const short8*)&Blds[(ch * 64 + nt * 16 + m) * 128 + pc];
        qa[nt] = __builtin_amdgcn_mfma_f32_16x16x32_bf16(af, bf, qa[nt], 0, 0, 0);
      }
    }
    #pragma unroll
    for (int nt = 0; nt < 4; ++nt) {
      int col = c3 * 128 + ch * 64 + nt * 16 + m;
      #pragma unroll
      for (int r = 0; r < 4; ++r) {
        int row = row0 + rt * 16 + quad * 4 + r;
        qkvb[(size_t)row * 384 + col] = f2bf(qa[nt][r]);
      }
    }
  }
}

// ---------------- fused transformer tail for one layer, 32 rows/block:
//   1. Wo GEMM (split-K attention combine as A) + residual (register-carried)
//   2. LN2 -> Ylds   3. MLP (h in LDS) + residual -> tokens
//   4a. [layer 0] LN1 -> Ylds, next-layer QKV GEMM -> qkvb
//   4b. [layer 1] decoder-head GEMV (tokens . dWc/dWf + bias) -> hrow
__global__ __launch_bounds__(256) void k_fused(const short* __restrict__ Opart,
    const float* __restrict__ Lpart, const short* __restrict__ WtO,
    const float* __restrict__ bo_, const float* __restrict__ ln2g_,
    const float* __restrict__ ln2b_, const short* __restrict__ Wt1,
    const float* __restrict__ b1_, const short* __restrict__ Wt2,
    const float* __restrict__ b2_, float* __restrict__ tokens,
    const float* __restrict__ ln1g_, const float* __restrict__ ln1b_,
    const short* __restrict__ WtQ, short* __restrict__ qkvb,
    const float* __restrict__ dWc_, const float* __restrict__ dbc_,
    const float* __restrict__ dWf_, const float* __restrict__ dbf_,
    float* __restrict__ hrow) {
  __shared__ short Blds[128 * 128];   // staged weight chunk (Wo / W1 / W2 / WtQ)
  __shared__ short AH[32 * 268];      // aliased: Wo-A (stride 136) then H (stride 268)
  __shared__ short Ylds[32 * 136];    // LN'd activations (LN2 y, later LN1 y)
  __shared__ float pls[2][32], plq[2][32];
  int row0 = blockIdx.x * 32;
  int b = row0 / NTOK;
  int rloc = row0 % NTOK;
  int qt = rloc >> 6, qoff = rloc & 63;   // 0 or 32
  int t = threadIdx.x;
  int lane = t & 63, w = t >> 6;
  int m = lane & 15, quad = lane >> 4;
  int rt = w >> 1, ch = w & 1;
  int lrow = lane >> 4, jphys = lane & 15;
  f32x4 zero = {0.f, 0.f, 0.f, 0.f};

  // ---- Wo B staging (DMA), overlaps A combine below
  #pragma unroll
  for (int j = 0; j < 8; ++j) {
    int c = j * 4 + w;                 // 0..31 (4 rows each)
    int r = c * 4 + lrow;
    int jlog = jphys ^ (r & 15);
    __builtin_amdgcn_global_load_lds(
        (const unsigned*)&WtO[(size_t)r * 128 + jlog * 8],
        (unsigned*)&Blds[c * 512], 16, 0, 0);
  }
  // ---- A staging: combine split-K attention partials, normalize by L
  #pragma unroll
  for (int it = 0; it < 2; ++it) {
    int idx = t + it * 256;            // 512 short8 chunks (32 rows x 16)
    int q = idx >> 4, j = idx & 15;
    int dh = j >> 2, dd = (j & 3) * 8;
    int qg = qoff + q;                 // q within the 64-row attention tile
    size_t pb = ((size_t)(b * HEADS + dh) * NQT + qt) * SPLIT;
    float L = 0.f;
    #pragma unroll
    for (int sk = 0; sk < SPLIT; ++sk) L += Lpart[(pb + sk) * 64 + qg];
    float o[8] = {0, 0, 0, 0, 0, 0, 0, 0};
    #pragma unroll
    for (int sk = 0; sk < SPLIT; ++sk) {
      short8 po = *(const short8*)&Opart[(pb + sk) * 2048 + qg * 32 + dd];
      #pragma unroll
      for (int i = 0; i < 8; ++i) o[i] += bf2f(po[i]);
    }
    float rs = 1.f / L;
    short8 ov;
    #pragma unroll
    for (int i = 0; i < 8; ++i) ov[i] = f2bf(o[i] * rs);
    *(short8*)&AH[q * 136 + j * 8] = ov;
  }
  __syncthreads();
  // ---- Wo GEMM
  f32x4 acc[4] = {zero, zero, zero, zero};
  #pragma unroll
  for (int ks = 0; ks < 4; ++ks) {
    short8 af = *(const short8*)&AH[(rt * 16 + m) * 136 + quad * 8 + ks * 32];
    int pc = ((quad + ks * 4) ^ m) * 8;
    #pragma unroll
    for (int nt = 0; nt < 4; ++nt) {
      short8 bf = *(const short8*)&Blds[(ch * 64 + nt * 16 + m) * 128 + pc];
      acc[nt] = __builtin_amdgcn_mfma_f32_16x16x32_bf16(af, bf, acc[nt], 0, 0, 0);
    }
  }
  // ---- residual (register-carried) + LN2 stats
  float v[4][4];
  #pragma unroll
  for (int nt = 0; nt < 4; ++nt) {
    int col = ch * 64 + nt * 16 + m;
    float bv = bo_[col];
    #pragma unroll
    for (int r = 0; r < 4; ++r) {
      int row = row0 + rt * 16 + quad * 4 + r;
      v[nt][r] = acc[nt][r] + bv + tokens[(size_t)row * DD + col];
    }
  }
  #pragma unroll
  for (int r = 0; r < 4; ++r) {
    float s = v[0][r] + v[1][r] + v[2][r] + v[3][r];
    float q = v[0][r] * v[0][r] + v[1][r] * v[1][r]
            + v[2][r] * v[2][r] + v[3][r] * v[3][r];
    #pragma unroll
    for (int o = 1; o < 16; o <<= 1) { s += __shfl_xor(s, o); q += __shfl_xor(q, o); }
    if (m == 0) {
      int lr = rt * 16 + quad * 4 + r;
      pls[ch][lr] = s;
      plq[ch][lr] = q;
    }
  }
  __syncthreads();   // stats published; all Wo Blds/AH reads drained
  // ---- W1 half-0 DMA now (overlaps LN2 apply)
  #pragma unroll
  for (int j = 0; j < 8; ++j) {
    int c = j * 4 + w;
    int r = c * 4 + lrow;
    int jlog = jphys ^ (r & 15);
    __builtin_amdgcn_global_load_lds(
        (const unsigned*)&Wt1[(size_t)r * 128 + jlog * 8],
        (unsigned*)&Blds[c * 512], 16, 0, 0);
  }
  // ---- LN2 apply -> Ylds
  #pragma unroll
  for (int r = 0; r < 4; ++r) {
    int lr = rt * 16 + quad * 4 + r;
    float S = pls[0][lr] + pls[1][lr];
    float Q = plq[0][lr] + plq[1][lr];
    float mean = S * (1.f / 128.f);
    float var = Q * (1.f / 128.f) - mean * mean;
    float rstd = rsqrtf(var + 1e-5f);
    #pragma unroll
    for (int nt = 0; nt < 4; ++nt) {
      int col = ch * 64 + nt * 16 + m;
      Ylds[lr * 136 + col] = f2bf((v[nt][r] - mean) * rstd * ln2g_[col] + ln2b_[col]);
    }
  }
  // ---- MLP: h = gelu(y @ W1 + b1) -> AH (stride 268)
  for (int hh = 0; hh < 2; ++hh) {
    if (hh) {
      __syncthreads();                 // half-0 Blds reads drained
      #pragma unroll
      for (int j = 0; j < 8; ++j) {
        int c = j * 4 + w;
        int r = c * 4 + lrow;
        int jlog = jphys ^ (r & 15);
        __builtin_amdgcn_global_load_lds(
            (const unsigned*)&Wt1[(size_t)(128 + r) * 128 + jlog * 8],
            (unsigned*)&Blds[c * 512], 16, 0, 0);
      }
    }
    __syncthreads();   // DMA drained (+ Ylds published on hh=0)
    f32x4 ha[4] = {zero, zero, zero, zero};
    #pragma unroll
    for (int ks = 0; ks < 4; ++ks) {
      short8 af = *(const short8*)&Ylds[(rt * 16 + m) * 136 + quad * 8 + ks * 32];
      int pc = ((quad + ks * 4) ^ m) * 8;
      #pragma unroll
      for (int nt = 0; nt < 4; ++nt) {
        short8 bf = *(const short8*)&Blds[(ch * 64 + nt * 16 + m) * 128 + pc];
        ha[nt] = __builtin_amdgcn_mfma_f32_16x16x32_bf16(af, bf, ha[nt], 0, 0, 0);
      }
    }
    #pragma unroll
    for (int nt = 0; nt < 4; ++nt) {
      int n = hh * 128 + ch * 64 + nt * 16 + m;
      float bv = b1_[n];
      #pragma unroll
      for (int r = 0; r < 4; ++r) {
        float vv = ha[nt][r] + bv;
        vv = 0.5f * vv * (1.f + erff(vv * 0.70710678118654752f));
        AH[(rt * 16 + quad * 4 + r) * 268 + n] = f2bf(vv);
      }
    }
  }
  // ---- W2: K=256 in two chunks (chunk kb == H half kb)
  f32x4 a2[4] = {zero, zero, zero, zero};
  for (int kb = 0; kb < 2; ++kb) {
    __syncthreads();                   // Blds reads drained + H published
    #pragma unroll
    for (int j = 0; j < 8; ++j) {
      int c = j * 4 + w;
      int r = c * 4 + lrow;
      int jlog = jphys ^ (r & 15);
      __builtin_amdgcn_global_load_lds(
          (const unsigned*)&Wt2[(size_t)r * 256 + kb * 128 + jlog * 8],
          (unsigned*)&Blds[c * 512], 16, 0, 0);
    }
    __syncthreads();
    #pragma unroll
    for (int ks = 0; ks < 4; ++ks) {
      int pc = ((quad + ks * 4) ^ m) * 8;
      short8 af = *(const short8*)&AH[(rt * 16 + m) * 268 + kb * 128
                                      + quad * 8 + ks * 32];
      #pragma unroll
      for (int nt = 0; nt < 4; ++nt) {
        short8 bf = *(const short8*)&Blds[(ch * 64 + nt * 16 + m) * 128 + pc];
        a2[nt] = __builtin_amdgcn_mfma_f32_16x16x32_bf16(af, bf, a2[nt], 0, 0, 0);
      }
    }
  }
  // ---- MLP epilogue: residual from registers, single tokens write
  #pragma unroll
  for (int nt = 0; nt < 4; ++nt) {
    int col = ch * 64 + nt * 16 + m;
    float bv = b2_[col];
    #pragma unroll
    for (int r = 0; r < 4; ++r) {
      int row = row0 + rt * 16 + quad * 4 + r;
      float val = a2[nt][r] + bv + v[nt][r];
      tokens[(size_t)row * DD + col] = val;
      v[nt][r] = val;
    }
  }
  if (ln1g_ == nullptr) {
    // ---- layer-1 tail: decoder-head GEMV fused (tokens . dWc/dWf + bias)
    bool coarse = (rloc < NCc);        // block-uniform (NC multiple of 32)
    const float* dw = coarse ? dWc_ : dWf_;
    float dwv[4];
    #pragma unroll
    for (int nt = 0; nt < 4; ++nt) dwv[nt] = dw[ch * 64 + nt * 16 + m];
    #pragma unroll
    for (int r = 0; r < 4; ++r) {
      float s = v[0][r] * dwv[0] + v[1][r] * dwv[1]
              + v[2][r] * dwv[2] + v[3][r] * dwv[3];
      #pragma unroll
      for (int o = 1; o < 16; o <<= 1) s += __shfl_xor(s, o);
      if (m == 0) pls[ch][rt * 16 + quad * 4 + r] = s;
    }
    __syncthreads();
    if (m == 0 && ch == 0) {
      float dbv = coarse ? dbc_[0] : dbf_[0];
      #pragma unroll
      for (int r = 0; r < 4; ++r) {
        int lr = rt * 16 + quad * 4 + r;
        hrow[row0 + lr] = pls[0][lr] + pls[1][lr] + dbv;
      }
    }
    return;
  }
  // ---- LN1 stats (layer 0 only)
  #pragma unroll
  for (int r = 0; r < 4; ++r) {
    float s = v[0][r] + v[1][r] + v[2][r] + v[3][r];
    float q = v[0][r] * v[0][r] + v[1][r] * v[1][r]
            + v[2][r] * v[2][r] + v[3][r] * v[3][r];
    #pragma unroll
    for (int o = 1; o < 16; o <<= 1) { s += __shfl_xor(s, o); q += __shfl_xor(q, o); }
    if (m == 0) {
      int lr = rt * 16 + quad * 4 + r;
      pls[ch][lr] = s;
      plq[ch][lr] = q;
    }
  }
  __syncthreads();   // stats published + W2 Blds reads drained
  // ---- QKV chunk-0 DMA now (overlaps LN1 apply)
  #pragma unroll
  for (int j = 0; j < 8; ++j) {
    int c = j * 4 + w;
    int r = c * 4 + lrow;
    int jlog = jphys ^ (r & 15);
    __builtin_amdgcn_global_load_lds(
        (const unsigned*)&WtQ[(size_t)r * 128 + jlog * 8],
        (unsigned*)&Blds[c * 512], 16, 0, 0);
  }
  #pragma unroll
  for (int r = 0; r < 4; ++r) {
    int lr = rt * 16 + quad * 4 + r;
    float S = pls[0][lr] + pls[1][lr];
    float Q = plq[0][lr] + plq[1][lr];
    float mean = S * (1.f / 128.f);
    float var = Q * (1.f / 128.f) - mean * mean;
    float rstd = rsqrtf(var + 1e-5f);
    #pragma unroll
    for (int nt = 0; nt < 4; ++nt) {
      int col = ch * 64 + nt * 16 + m;
      Ylds[lr * 136 + col] = f2bf((v[nt][r] - mean) * rstd * ln1g_[col] + ln1b_[col]);
    }
  }
  // ---- next-layer QKV GEMM: 3 chunks of 128 output cols
  for (int c3 = 0; c3 < 3; ++c3) {
    if (c3) {
      __syncthreads();
      #pragma unroll
      for (int j = 0; j < 8; ++j) {
        int c = j * 4 + w;
        int r = c * 4 + lrow;
        int jlog = jphys ^ (r & 15);
        __builtin_amdgcn_global_load_lds(
            (const unsigned*)&WtQ[(size_t)(c3 * 128 + r) * 128 + jlog * 8],
            (unsigned*)&Blds[c * 512], 16, 0, 0);
      }
    }
    __syncthreads();   // DMA drained (+ Ylds published on c3=0)
    f32x4 qa[4] = {zero, zero, zero, zero};
    #pragma unroll
    for (int ks = 0; ks < 4; ++ks) {
      short8 af = *(const short8*)&Ylds[(rt * 16 + m) * 136 + quad * 8 + ks * 32];
      int pc = ((quad + ks * 4) ^ m) * 8;
      #pragma unroll
      for (int nt = 0; nt < 4; ++nt) {
        short8 bf = *(const short8*)&Blds[(ch * 64 + nt * 16 + m) * 128 + pc];
        qa[nt] = __builtin_amdgcn_mfma_f32_16x16x32_bf16(af, bf, qa[nt], 0, 0, 0);
      }
    }
    #pragma unroll
    for (int nt = 0; nt < 4; ++nt) {
      int col = c3 * 128 + ch * 64 + nt * 16 + m;
      #pragma unroll
      for (int r = 0; r < 4; ++r) {
        int row = row0 + rt * 16 + quad * 4 + r;
        qkvb[(size_t)row * 384 + col] = f2bf(qa[nt][r]);
      }
    }
  }
}

// ---------------- flash attention: split-K (SPLIT=2), fixed-max softmax,
// double-buffered K/V (one barrier/stage, prefetch issued before compute so
// K-DMA + V-load latency hides under MFMA+softmax), XCD-chunked block swizzle
// (all 40 blocks of one (b,h) land on XCD g%8 -> K/V panel L2-resident once).
__global__ __launch_bounds__(256) void k_attn4(const short* __restrict__ qkv,
    short* __restrict__ Opart, float* __restrict__ Lpart) {
  __shared__ short Ks[2][64 * 32];   // [key][d], DMA, chunk swizzle f(k)=(k>>1)&3
  __shared__ short Vt[2][32 * 74];   // [d][key], stride 74 (free scatter+gather)
  __shared__ short Pl[4][16 * 74];   // per-wave P [q][key]

  // XCD-chunked decode: hw id = k*32 + g  (g = (b,h) group, k = 40 tiles)
  // hardware XCD = hid % 8 = g % 8 -> per-XCD K/V panel reuse
  int hid = blockIdx.x;
  int g = hid & 31;                  // (b,h) group 0..31
  int k = hid >> 5;                  // 0..39
  int b = g >> 2, h = g & 3;         // HEADS = 4
  int qt = k / SPLIT, sk = k % SPLIT;
  size_t lid = ((size_t)g * NQT + qt) * SPLIT + sk;   // logical output slot
  int t = threadIdx.x;
  int lane = t & 63, w = t >> 6;
  int m = lane & 15, quad = lane >> 4;
  int q0 = qt * 64 + w * 16;

  const float scale = 0.17677669529663687f;  // 1/sqrt(32), folded into Q
  short8 qraw = *(const short8*)(qkv + ((size_t)(b * NTOK) + q0 + m) * 384 + h * HD + quad * 8);
  short8 qf;
  #pragma unroll
  for (int j = 0; j < 8; ++j) qf[j] = f2bf(bf2f(qraw[j]) * scale);

  f32x4 zero = {0.f, 0.f, 0.f, 0.f};
  f32x4 Oacc[2] = {zero, zero};
  float psum[4] = {0.f, 0.f, 0.f, 0.f};

  int skey = t >> 2, sdseg = t & 3;  // staging: key 0..63, 8 dims each
  int jlogK = sdseg ^ ((skey >> 1) & 3);
  const short* kstage = qkv + ((size_t)(b * NTOK) + skey) * 384 + 128 + h * HD + jlogK * 8;
  const short* vstage = qkv + ((size_t)(b * NTOK) + skey) * 384 + 256 + h * HD + sdseg * 8;
  int kswz = (quad ^ ((m >> 1) & 3)) * 8;   // read-side physical chunk offset

  int s0 = sk * NSTG;
  // ---- prologue: stage s0 into buffer 0
  __builtin_amdgcn_global_load_lds((const unsigned*)(kstage + (size_t)s0 * 64 * 384),
                                   (unsigned*)&Ks[0][w * 512], 16, 0, 0);
  {
    short8 vf = *(const short8*)(vstage + (size_t)s0 * 64 * 384);
    #pragma unroll
    for (int j = 0; j < 8; ++j) Vt[0][(sdseg * 8 + j) * 74 + skey] = vf[j];
  }
  __syncthreads();   // K DMA + V scatter of stage 0 complete

  for (int i = 0; i < NSTG; ++i) {
    int cur = i & 1;
    short8 vf;
    if (i + 1 < NSTG) {
      // prefetch next stage BEFORE compute: K-DMA into other buffer, V to regs
      __builtin_amdgcn_global_load_lds(
          (const unsigned*)(kstage + (size_t)(s0 + i + 1) * 64 * 384),
          (unsigned*)&Ks[cur ^ 1][w * 512], 16, 0, 0);
      vf = *(const short8*)(vstage + (size_t)(s0 + i + 1) * 64 * 384);
    }

    // S = Q K^T (C-layout: row=4*quad+reg, col=m); Q pre-scaled
    f32x4 sc[4];
    #pragma unroll
    for (int ct = 0; ct < 4; ++ct) {
      short8 kfrag = *(const short8*)&Ks[cur][(ct * 16 + m) * 32 + kswz];
      sc[ct] = __builtin_amdgcn_mfma_f32_16x16x32_bf16(qf, kfrag, zero, 0, 0, 0);
    }
    // fixed-max softmax: p = exp(s); l accumulated from TRUNCATED p (bias-free)
    #pragma unroll
    for (int ct = 0; ct < 4; ++ct)
      #pragma unroll
      for (int r = 0; r < 4; ++r) {
        float p = __expf(sc[ct][r]);
        unsigned u = __builtin_bit_cast(unsigned, p);
        psum[r] += __builtin_bit_cast(float, u & 0xffff0000u);
        Pl[w][(quad * 4 + r) * 74 + ct * 16 + m] = (short)(u >> 16);
      }
    // O += P @ V
    #pragma unroll
    for (int ks = 0; ks < 2; ++ks) {
      short8 pfrag = *(const short8*)&Pl[w][m * 74 + ks * 32 + quad * 8];
      #pragma unroll
      for (int nt = 0; nt < 2; ++nt) {
        short8 vfrag = *(const short8*)&Vt[cur][(nt * 16 + m) * 74 + ks * 32 + quad * 8];
        Oacc[nt] = __builtin_amdgcn_mfma_f32_16x16x32_bf16(pfrag, vfrag, Oacc[nt], 0, 0, 0);
      }
    }
    if (i + 1 < NSTG) {
      // write-late: scatter prefetched V into the other buffer
      #pragma unroll
      for (int j = 0; j < 8; ++j) Vt[cur ^ 1][(sdseg * 8 + j) * 74 + skey] = vf[j];
    }
    __syncthreads();   // next-stage K DMA drained + V scatter published
  }
  // single final ladder per row; write partial O (unnormalized) + l
  #pragma unroll
  for (int r = 0; r < 4; ++r) {
    float ssum = psum[r];
    #pragma unroll
    for (int o = 1; o < 16; o <<= 1) ssum += __shfl_xor(ssum, o);
    int qloc = w * 16 + quad * 4 + r;
    #pragma unroll
    for (int nt = 0; nt < 2; ++nt)
      Opart[lid * 2048 + qloc * 32 + nt * 16 + m] = f2bf(Oacc[nt][r]);
    if (m == 0) Lpart[lid * 64 + qloc] = ssum;
  }
}

// ---------------- fused decoder: reads precomputed head scalars (hrow),
// scatter + bilinear + conv3x3+relu+conv3x3 — one block per image
__global__ __launch_bounds__(1024) void k_decoder(const float* __restrict__ hrow,
    const float* __restrict__ msort, const int* __restrict__ order,
    const float* __restrict__ fW1, const float* __restrict__ fb1,
    const float* __restrict__ fW2, const float* __restrict__ fb2,
    float* __restrict__ outp) {
  int b = blockIdx.x;
  int t = threadIdx.x;
  __shared__ float cmap[NCc];
  __shared__ float fmap[1024];
  __shared__ float cup[1024];
  __shared__ float hb[2][1024];
  fmap[order[b * NFf + t]] = hrow[b * NTOK + NCc + t] * msort[b * NFf + t];
  if (t < NCc) cmap[t] = hrow[b * NTOK + t];
  __syncthreads();
  int y = t >> 5, x = t & 31;
  {
    float ys = y * (15.f / 31.f);
    float xs = x * (15.f / 31.f);
    int y0 = (int)floorf(ys); int y1 = min(y0 + 1, 15); float wy = ys - (float)y0;
    int x0 = (int)floorf(xs); int x1 = min(x0 + 1, 15); float wx = xs - (float)x0;
    cup[t] = cmap[y0 * 16 + x0] * (1.f - wy) * (1.f - wx)
           + cmap[y0 * 16 + x1] * (1.f - wy) * wx
           + cmap[y1 * 16 + x0] * wy * (1.f - wx)
           + cmap[y1 * 16 + x1] * wy * wx;
  }
  __syncthreads();
  for (int oc = 0; oc < 2; ++oc) {
    float a = fb1[oc];
    #pragma unroll
    for (int ic = 0; ic < 2; ++ic)
      #pragma unroll
      for (int ky = 0; ky < 3; ++ky)
        #pragma unroll
        for (int kx = 0; kx < 3; ++kx) {
          int yy = y + ky - 1, xx = x + kx - 1;
          float v = 0.f;
          if (yy >= 0 && yy < 32 && xx >= 0 && xx < 32)
            v = ic == 0 ? cup[yy * 32 + xx] : fmap[yy * 32 + xx];
          a += v * fW1[((oc * 2 + ic) * 3 + ky) * 3 + kx];
        }
    hb[oc][t] = fmaxf(a, 0.f);
  }
  __syncthreads();
  float a = fb2[0];
  #pragma unroll
  for (int ic = 0; ic < 2; ++ic)
    #pragma unroll
    for (int ky = 0; ky < 3; ++ky)
      #pragma unroll
      for (int kx = 0; kx < 3; ++kx) {
        int yy = y + ky - 1, xx = x + kx - 1;
        float v = (yy >= 0 && yy < 32 && xx >= 0 && xx < 32)
                      ? hb[ic][yy * 32 + xx] : 0.f;
        a += v * fW2[(ic * 3 + ky) * 3 + kx];
      }
  outp[b * 1024 + t] = a;
}

extern "C" void kernel_launch(void* const* d_in, const int* in_sizes, int n_in,
                              void* d_out, int out_size, void* d_ws, size_t ws_size,
                              hipStream_t stream) {
  const float* x    = (const float*)d_in[0];
  const float* Wpc  = (const float*)d_in[1];
  const float* bpc  = (const float*)d_in[2];
  const float* Wpf  = (const float*)d_in[3];
  const float* bpf  = (const float*)d_in[4];
  const float* te   = (const float*)d_in[5];
  const float* ln1g = (const float*)d_in[6];
  const float* ln1b = (const float*)d_in[7];
  const float* Wqkv = (const float*)d_in[8];
  const float* Wo   = (const float*)d_in[9];
  const float* bo   = (const float*)d_in[10];
  const float* ln2g = (const float*)d_in[11];
  const float* ln2b = (const float*)d_in[12];
  const float* W1   = (const float*)d_in[13];
  const float* b1   = (const float*)d_in[14];
  const float* W2   = (const float*)d_in[15];
  const float* b2   = (const float*)d_in[16];
  const float* dWc  = (const float*)d_in[17];
  const float* dbc  = (const float*)d_in[18];
  const float* dWf  = (const float*)d_in[19];
  const float* dbf  = (const float*)d_in[20];
  const float* fW1  = (const float*)d_in[21];
  const float* fb1  = (const float*)d_in[22];
  const float* fW2  = (const float*)d_in[23];
  const float* fb2  = (const float*)d_in[24];

  char* ws = (char*)d_ws;
  float* tokens = (float*)ws;                 ws += 1310720 * 4;   // fp32 [B*N,128]
  float* fineb  = (float*)ws;                 ws += 1048576 * 4;   // fp32 [B*NF,128]
  short* qkvb   = (short*)ws;                 ws += 3932160 * 2;   // bf16 [B*N,384]
  short* Opart  = (short*)ws;                 ws += (size_t)(Bx * HEADS * NQT * SPLIT) * 2048 * 2;
  float* Lpart  = (float*)ws;                 ws += (size_t)(Bx * HEADS * NQT * SPLIT) * 64 * 4;
  short* WtQKV  = (short*)ws;                 ws += 98304 * 2;     // [L][384][128]
  short* WtO    = (short*)ws;                 ws += 32768 * 2;     // [L][128][128]
  short* Wt1    = (short*)ws;                 ws += 65536 * 2;     // [L][256][128]
  short* Wt2    = (short*)ws;                 ws += 65536 * 2;     // [L][128][256]
  float* ebuf   = (float*)ws;                 ws += 8192 * 4;
  float* msort  = (float*)ws;                 ws += 8192 * 4;
  int*   order  = (int*)ws;                   ws += 8192 * 4;
  float* hrow   = (float*)ws;                 ws += 10240 * 4;     // decoder-head scalars

  const int M = Bx * NTOK;                    // 10240

  k_prologue<<<6656, 256, 0, stream>>>(x, Wpc, bpc, Wpf, bpf, te, Wqkv, Wo, W1, W2,
                                       WtQKV, WtO, Wt1, Wt2, ebuf, tokens, fineb);
  k_edge_sort<<<Bx, 1024, 0, stream>>>(ebuf, order, msort);
  k_gather_qkv<<<M / 32, 256, 0, stream>>>(tokens, fineb, order, msort, te,
                                           ln1g, ln1b, WtQKV, qkvb);

  // layer 0: attn -> fused[Wo+LN2+MLP+LN1+QKV(l1)]
  k_attn4<<<Bx * HEADS * NQT * SPLIT, 256, 0, stream>>>(qkvb, Opart, Lpart);
  k_fused<<<M / 32, 256, 0, stream>>>(
      Opart, Lpart, WtO, bo, ln2g, ln2b,
      Wt1, b1, Wt2, b2, tokens,
      ln1g + DD, ln1b + DD, WtQKV + 49152, qkvb,
      nullptr, nullptr, nullptr, nullptr, nullptr);

  // layer 1: attn -> fused[Wo+LN2+MLP+decoder-head]
  k_attn4<<<Bx * HEADS * NQT * SPLIT, 256, 0, stream>>>(qkvb, Opart, Lpart);
  k_fused<<<M / 32, 256, 0, stream>>>(
      Opart, Lpart, WtO + 16384, bo + DD, ln2g + DD, ln2b + DD,
      Wt1 + 32768, b1 + 256, Wt2 + 32768, b2 + DD, tokens,
      nullptr, nullptr, nullptr, nullptr,
      dWc, dbc, dWf, dbf, hrow);

  k_decoder<<<Bx, 1024, 0, stream>>>(hrow, msort, order,
                                     fW1, fb1, fW2, fb2, (float*)d_out);
}

// Round 6
// 212.116 us; speedup vs baseline: 1.5067x; 1.0298x over previous
//
#include <hip/hip_runtime.h>
#include <math.h>

#define Bx 8
#define IMG 128
#define DD 128
#define HEADS 4
#define LL 2
#define PCc 8
#define PFf 4
#define HCc 16
#define NCc 256
#define HFf 32
#define NFf 1024
#define NTOK 1280
#define HD 32
#define SPLIT 2          // key-split factor for flash-decode attention
#define NSTG 10          // stages per split = NTOK/64/SPLIT
#define NQT 20           // NTOK/64 query tiles

typedef __attribute__((ext_vector_type(8))) short short8;
typedef __attribute__((ext_vector_type(4))) float f32x4;

__device__ __forceinline__ short f2bf(float f) {
  unsigned u = __builtin_bit_cast(unsigned, f);
  u += 0x7FFF + ((u >> 16) & 1);   // RNE
  return (short)(u >> 16);
}
__device__ __forceinline__ float bf2f(short s) {
  unsigned u = ((unsigned)(unsigned short)s) << 16;
  return __builtin_bit_cast(float, u);
}

// ---------------- batched prologue: [0,1024) prep_w, [1024,1536) sobel,
// [1536,2560) coarse embed (2 tok/block), [2560,6656) fine embed -> fineb
__global__ __launch_bounds__(256) void k_prologue(const float* __restrict__ x,
    const float* __restrict__ Wpc, const float* __restrict__ bpc,
    const float* __restrict__ Wpf, const float* __restrict__ bpf,
    const float* __restrict__ te,
    const float* __restrict__ Wqkv, const float* __restrict__ Wo,
    const float* __restrict__ W1, const float* __restrict__ W2,
    short* __restrict__ WtQKV, short* __restrict__ WtO,
    short* __restrict__ Wt1, short* __restrict__ Wt2,
    float* __restrict__ e, float* __restrict__ tokens,
    float* __restrict__ fineb) {
  int blk = blockIdx.x;
  int t = threadIdx.x;
  if (blk < 1024) {
    // ---- weight prep: transpose + bf16
    int idx = blk * 256 + t;   // 0 .. 262143
    int l = idx / 131072, r = idx % 131072;
    const float* src; short* dst; int N, off;
    if (r < 49152)      { src = Wqkv + l * 49152; dst = WtQKV + l * 49152; N = 384; off = r; }
    else if (r < 65536) { src = Wo + l * 16384;  dst = WtO + l * 16384;  N = 128; off = r - 49152; }
    else if (r < 98304) { src = W1 + l * 32768;  dst = Wt1 + l * 32768;  N = 256; off = r - 65536; }
    else                { src = W2 + l * 32768;  dst = Wt2 + l * 32768;  N = 128; off = r - 98304; }
    int k = off / N, n = off % N;
    int K = (r >= 98304) ? 256 : 128;
    dst[(size_t)n * K + k] = f2bf(src[off]);
  } else if (blk < 1536) {
    // ---- sobel + 4x4 avgpool -> cell energy
    int bt = blk - 1024;
    int b = bt >> 6, tile = bt & 63;
    int ty = tile >> 3, tx = tile & 7;
    int ly = t >> 4, lx = t & 15;
    int py = ty * 16 + ly, px = tx * 16 + lx;
    const float* img = x + (size_t)b * IMG * IMG;
    float v[3][3];
    #pragma unroll
    for (int ky = 0; ky < 3; ++ky)
      #pragma unroll
      for (int kx = 0; kx < 3; ++kx) {
        int yy = py + ky - 1, xx = px + kx - 1;
        v[ky][kx] = (yy >= 0 && yy < IMG && xx >= 0 && xx < IMG)
                        ? img[yy * IMG + xx] : 0.f;
      }
    float gx = -v[0][0] + v[0][2] - 2.f * v[1][0] + 2.f * v[1][2] - v[2][0] + v[2][2];
    float gy = -v[0][0] - 2.f * v[0][1] - v[0][2] + v[2][0] + 2.f * v[2][1] + v[2][2];
    __shared__ float sm[256];
    sm[t] = sqrtf(gx * gx + gy * gy);
    __syncthreads();
    if (t < 16) {
      int cy = t >> 2, cx = t & 3;
      float s = 0.f;
      #pragma unroll
      for (int dy = 0; dy < 4; ++dy)
        #pragma unroll
        for (int dx = 0; dx < 4; ++dx) s += sm[(cy * 4 + dy) * 16 + cx * 4 + dx];
      e[b * NFf + (ty * 4 + cy) * 32 + tx * 4 + cx] = s * (1.f / 16.f);
    }
  } else if (blk < 2560) {
    // ---- coarse patch embed, 2 tokens per block
    int bt = (blk - 1536) * 2 + (t >> 7);    // b*NC + tok
    int b = bt / NCc, tok = bt % NCc;
    int hc = tok / HCc, wc = tok % HCc;
    int half = t >> 7, d = t & 127;
    __shared__ float patch[2][PCc * PCc];
    if (d < PCc * PCc) {
      int pi = d / PCc, pj = d % PCc;
      patch[half][d] = x[(b * IMG + hc * PCc + pi) * IMG + wc * PCc + pj];
    }
    __syncthreads();
    float acc = bpc[d] + te[d];
    #pragma unroll 8
    for (int i = 0; i < PCc * PCc; ++i) acc += patch[half][i] * Wpc[i * DD + d];
    tokens[(size_t)(b * NTOK + tok) * DD + d] = acc;
  } else {
    // ---- fine patch embed, 2 tokens per block -> fineb (unsorted, unmasked)
    int ft = (blk - 2560) * 2 + (t >> 7);    // global fine token 0..8191
    int b = ft >> 10, tloc = ft & 1023;
    int hf = tloc >> 5, wf = tloc & 31;
    int half = t >> 7, d = t & 127;
    __shared__ float patch[2][PFf * PFf];
    if (d < PFf * PFf) {
      int pi = d / PFf, pj = d % PFf;
      patch[half][d] = x[(b * IMG + hf * PFf + pi) * IMG + wf * PFf + pj];
    }
    __syncthreads();
    float acc = bpf[d];
    #pragma unroll
    for (int i = 0; i < PFf * PFf; ++i) acc += patch[half][i] * Wpf[i * DD + d];
    fineb[(size_t)(b * NFf + tloc) * DD + d] = acc;
  }
}

// ---------------- mask at per-image mean -> stable-sort order via ballot scan
__global__ __launch_bounds__(1024) void k_edge_sort(const float* __restrict__ e,
    int* __restrict__ order, float* __restrict__ msort) {
  int b = blockIdx.x;
  int t = threadIdx.x;
  int lane = t & 63, wave = t >> 6;
  float ev = e[b * NFf + t];
  __shared__ float wsum[16];
  __shared__ int wcnt[16];
  float r = ev;
  #pragma unroll
  for (int o = 32; o > 0; o >>= 1) r += __shfl_xor(r, o, 64);
  if (lane == 0) wsum[wave] = r;
  __syncthreads();
  float tot = 0.f;
  #pragma unroll
  for (int i = 0; i < 16; ++i) tot += wsum[i];
  float mean = tot * (1.f / 1024.f);
  int m = (ev > mean) ? 1 : 0;
  unsigned long long bal = __ballot(m);
  if (lane == 0) wcnt[wave] = __popcll(bal);
  __syncthreads();
  int wbase = 0, total = 0;
  #pragma unroll
  for (int i = 0; i < 16; ++i) {
    int c = wcnt[i];
    if (i < wave) wbase += c;
    total += c;
  }
  unsigned long long below = (lane == 63) ? ~0ULL : ((1ULL << (lane + 1)) - 1);
  int incl = __popcll(bal & below);
  int eb = wbase + incl - m;       // edges strictly before t
  int pos = m ? eb : (total + t - eb);
  order[b * NFf + pos] = t;
  msort[b * NFf + pos] = (float)m;
}

// ---------------- gather + LN1 + layer-0 QKV GEMM, 16 rows/block (640 blocks,
// ~4 blocks/CU resident -> co-resident blocks cover each other's phase stalls)
__global__ __launch_bounds__(256) void k_gather_qkv(float* __restrict__ tokens,
    const float* __restrict__ fineb, const int* __restrict__ order,
    const float* __restrict__ msort, const float* __restrict__ te,
    const float* __restrict__ g, const float* __restrict__ bb,
    const short* __restrict__ WtQ, short* __restrict__ qkvb) {
  __shared__ short Blds[128 * 128];
  __shared__ short Ylds[16 * 136];
  int row0 = blockIdx.x * 16;
  int t = threadIdx.x;
  int lane = t & 63, w = t >> 6;
  int m = lane & 15, quad = lane >> 4;
  int lrow = lane >> 4, jphys = lane & 15;
  f32x4 zero = {0.f, 0.f, 0.f, 0.f};

  // ---- issue QKV chunk-0 weight DMA now; drains at the first barrier
  #pragma unroll
  for (int j = 0; j < 8; ++j) {
    int c = j * 4 + w;
    int r = c * 4 + lrow;
    int jlog = jphys ^ (r & 15);
    __builtin_amdgcn_global_load_lds(
        (const unsigned*)&WtQ[(size_t)r * 128 + jlog * 8],
        (unsigned*)&Blds[c * 512], 16, 0, 0);
  }
  // ---- phase A: gather + LN1 -> Ylds (4 rows per wave)
  float2 gg = ((const float2*)g)[lane];
  float2 bv = ((const float2*)bb)[lane];
  #pragma unroll
  for (int rr = 0; rr < 4; ++rr) {
    int lr = w * 4 + rr;
    int row = row0 + lr;
    int b = row / NTOK, rl = row % NTOK;
    float2 v;
    if (rl < NCc) {
      v = ((const float2*)(tokens + (size_t)row * DD))[lane];
    } else {
      int pos = rl - NCc;
      int src = order[b * NFf + pos];
      float mk = msort[b * NFf + pos];
      float2 u = ((const float2*)(fineb + (size_t)(b * NFf + src) * DD))[lane];
      float2 tv = ((const float2*)(te + DD))[lane];
      v.x = u.x * mk + tv.x;
      v.y = u.y * mk + tv.y;
      ((float2*)(tokens + (size_t)row * DD))[lane] = v;
    }
    float s = v.x + v.y;
    #pragma unroll
    for (int o = 32; o > 0; o >>= 1) s += __shfl_xor(s, o, 64);
    float mean = s * (1.f / 128.f);
    float cx = v.x - mean, cy = v.y - mean;
    float q = cx * cx + cy * cy;
    #pragma unroll
    for (int o = 32; o > 0; o >>= 1) q += __shfl_xor(q, o, 64);
    float rstd = rsqrtf(q * (1.f / 128.f) + 1e-5f);
    int p = (int)(unsigned short)f2bf(cx * rstd * gg.x + bv.x)
          | ((int)(unsigned short)f2bf(cy * rstd * gg.y + bv.y) << 16);
    ((int*)Ylds)[lr * 68 + lane] = p;
  }
  // ---- phase B: QKV GEMM, 3 chunks of 128 output cols
  // wave w covers output cols w*32 + nt*16 + m (nt<2); A rows are block rows
  for (int c3 = 0; c3 < 3; ++c3) {
    if (c3) {
      __syncthreads();
      #pragma unroll
      for (int j = 0; j < 8; ++j) {
        int c = j * 4 + w;
        int r = c * 4 + lrow;
        int jlog = jphys ^ (r & 15);
        __builtin_amdgcn_global_load_lds(
            (const unsigned*)&WtQ[(size_t)(c3 * 128 + r) * 128 + jlog * 8],
            (unsigned*)&Blds[c * 512], 16, 0, 0);
      }
    }
    __syncthreads();
    f32x4 qa[2] = {zero, zero};
    #pragma unroll
    for (int ks = 0; ks < 4; ++ks) {
      short8 af = *(const short8*)&Ylds[m * 136 + quad * 8 + ks * 32];
      int pc = ((quad + ks * 4) ^ m) * 8;
      #pragma unroll
      for (int nt = 0; nt < 2; ++nt) {
        short8 bf = *(const short8*)&Blds[(w * 32 + nt * 16 + m) * 128 + pc];
        qa[nt] = __builtin_amdgcn_mfma_f32_16x16x32_bf16(af, bf, qa[nt], 0, 0, 0);
      }
    }
    #pragma unroll
    for (int nt = 0; nt < 2; ++nt) {
      int col = c3 * 128 + w * 32 + nt * 16 + m;
      #pragma unroll
      for (int r = 0; r < 4; ++r) {
        int row = row0 + quad * 4 + r;
        qkvb[(size_t)row * 384 + col] = f2bf(qa[nt][r]);
      }
    }
  }
}

// ---------------- fused transformer tail for one layer, 16 rows/block
// (640 blocks, ~3 blocks/CU resident: phase-stall overlap via TLP):
//   1. Wo GEMM (split-K attention combine as A) + residual (register-carried)
//   2. LN2 -> Ylds   3. MLP (h in LDS) + residual -> tokens
//   4a. [layer 0] LN1 -> Ylds, next-layer QKV GEMM -> qkvb
//   4b. [layer 1] decoder-head GEMV (tokens . dWc/dWf + bias) -> hrow
__global__ __launch_bounds__(256) void k_fused(const short* __restrict__ Opart,
    const float* __restrict__ Lpart, const short* __restrict__ WtO,
    const float* __restrict__ bo_, const float* __restrict__ ln2g_,
    const float* __restrict__ ln2b_, const short* __restrict__ Wt1,
    const float* __restrict__ b1_, const short* __restrict__ Wt2,
    const float* __restrict__ b2_, float* __restrict__ tokens,
    const float* __restrict__ ln1g_, const float* __restrict__ ln1b_,
    const short* __restrict__ WtQ, short* __restrict__ qkvb,
    const float* __restrict__ dWc_, const float* __restrict__ dbc_,
    const float* __restrict__ dWf_, const float* __restrict__ dbf_,
    float* __restrict__ hrow) {
  __shared__ short Blds[128 * 128];   // staged weight chunk (Wo / W1 / W2 / WtQ)
  __shared__ short AH[16 * 268];      // aliased: Wo-A (stride 136) then H (stride 268)
  __shared__ short Ylds[16 * 136];    // LN'd activations (LN2 y, later LN1 y)
  __shared__ float pls[4][16], plq[4][16];
  int row0 = blockIdx.x * 16;
  int b = row0 / NTOK;
  int rloc = row0 % NTOK;
  int qt = rloc >> 6, qoff = rloc & 63;   // 0/16/32/48
  int t = threadIdx.x;
  int lane = t & 63, w = t >> 6;
  int m = lane & 15, quad = lane >> 4;
  int lrow = lane >> 4, jphys = lane & 15;
  f32x4 zero = {0.f, 0.f, 0.f, 0.f};

  // ---- Wo B staging (DMA), overlaps A combine below
  #pragma unroll
  for (int j = 0; j < 8; ++j) {
    int c = j * 4 + w;                 // 0..31 (4 rows each)
    int r = c * 4 + lrow;
    int jlog = jphys ^ (r & 15);
    __builtin_amdgcn_global_load_lds(
        (const unsigned*)&WtO[(size_t)r * 128 + jlog * 8],
        (unsigned*)&Blds[c * 512], 16, 0, 0);
  }
  // ---- A staging: combine split-K attention partials, normalize by L
  {
    int q = t >> 4, j = t & 15;        // 256 short8 chunks (16 rows x 16)
    int dh = j >> 2, dd = (j & 3) * 8;
    int qg = qoff + q;                 // q within the 64-row attention tile
    size_t pb = ((size_t)(b * HEADS + dh) * NQT + qt) * SPLIT;
    float L = 0.f;
    #pragma unroll
    for (int sk = 0; sk < SPLIT; ++sk) L += Lpart[(pb + sk) * 64 + qg];
    float o[8] = {0, 0, 0, 0, 0, 0, 0, 0};
    #pragma unroll
    for (int sk = 0; sk < SPLIT; ++sk) {
      short8 po = *(const short8*)&Opart[(pb + sk) * 2048 + qg * 32 + dd];
      #pragma unroll
      for (int i = 0; i < 8; ++i) o[i] += bf2f(po[i]);
    }
    float rs = 1.f / L;
    short8 ov;
    #pragma unroll
    for (int i = 0; i < 8; ++i) ov[i] = f2bf(o[i] * rs);
    *(short8*)&AH[q * 136 + j * 8] = ov;
  }
  __syncthreads();
  // ---- Wo GEMM: wave w covers cols w*32 + nt*16 + m (nt<2)
  f32x4 acc[2] = {zero, zero};
  #pragma unroll
  for (int ks = 0; ks < 4; ++ks) {
    short8 af = *(const short8*)&AH[m * 136 + quad * 8 + ks * 32];
    int pc = ((quad + ks * 4) ^ m) * 8;
    #pragma unroll
    for (int nt = 0; nt < 2; ++nt) {
      short8 bf = *(const short8*)&Blds[(w * 32 + nt * 16 + m) * 128 + pc];
      acc[nt] = __builtin_amdgcn_mfma_f32_16x16x32_bf16(af, bf, acc[nt], 0, 0, 0);
    }
  }
  // ---- residual (register-carried) + LN2 stats
  float v[2][4];
  #pragma unroll
  for (int nt = 0; nt < 2; ++nt) {
    int col = w * 32 + nt * 16 + m;
    float bv = bo_[col];
    #pragma unroll
    for (int r = 0; r < 4; ++r) {
      int row = row0 + quad * 4 + r;
      v[nt][r] = acc[nt][r] + bv + tokens[(size_t)row * DD + col];
    }
  }
  #pragma unroll
  for (int r = 0; r < 4; ++r) {
    float s = v[0][r] + v[1][r];
    float q = v[0][r] * v[0][r] + v[1][r] * v[1][r];
    #pragma unroll
    for (int o = 1; o < 16; o <<= 1) { s += __shfl_xor(s, o); q += __shfl_xor(q, o); }
    if (m == 0) {
      int lr = quad * 4 + r;
      pls[w][lr] = s;
      plq[w][lr] = q;
    }
  }
  __syncthreads();   // stats published; all Wo Blds/AH reads drained
  // ---- W1 half-0 DMA now (overlaps LN2 apply)
  #pragma unroll
  for (int j = 0; j < 8; ++j) {
    int c = j * 4 + w;
    int r = c * 4 + lrow;
    int jlog = jphys ^ (r & 15);
    __builtin_amdgcn_global_load_lds(
        (const unsigned*)&Wt1[(size_t)r * 128 + jlog * 8],
        (unsigned*)&Blds[c * 512], 16, 0, 0);
  }
  // ---- LN2 apply -> Ylds
  #pragma unroll
  for (int r = 0; r < 4; ++r) {
    int lr = quad * 4 + r;
    float S = pls[0][lr] + pls[1][lr] + pls[2][lr] + pls[3][lr];
    float Q = plq[0][lr] + plq[1][lr] + plq[2][lr] + plq[3][lr];
    float mean = S * (1.f / 128.f);
    float var = Q * (1.f / 128.f) - mean * mean;
    float rstd = rsqrtf(var + 1e-5f);
    #pragma unroll
    for (int nt = 0; nt < 2; ++nt) {
      int col = w * 32 + nt * 16 + m;
      Ylds[lr * 136 + col] = f2bf((v[nt][r] - mean) * rstd * ln2g_[col] + ln2b_[col]);
    }
  }
  // ---- MLP: h = gelu(y @ W1 + b1) -> AH (stride 268)
  for (int hh = 0; hh < 2; ++hh) {
    if (hh) {
      __syncthreads();                 // half-0 Blds reads drained
      #pragma unroll
      for (int j = 0; j < 8; ++j) {
        int c = j * 4 + w;
        int r = c * 4 + lrow;
        int jlog = jphys ^ (r & 15);
        __builtin_amdgcn_global_load_lds(
            (const unsigned*)&Wt1[(size_t)(128 + r) * 128 + jlog * 8],
            (unsigned*)&Blds[c * 512], 16, 0, 0);
      }
    }
    __syncthreads();   // DMA drained (+ Ylds published on hh=0)
    f32x4 ha[2] = {zero, zero};
    #pragma unroll
    for (int ks = 0; ks < 4; ++ks) {
      short8 af = *(const short8*)&Ylds[m * 136 + quad * 8 + ks * 32];
      int pc = ((quad + ks * 4) ^ m) * 8;
      #pragma unroll
      for (int nt = 0; nt < 2; ++nt) {
        short8 bf = *(const short8*)&Blds[(w * 32 + nt * 16 + m) * 128 + pc];
        ha[nt] = __builtin_amdgcn_mfma_f32_16x16x32_bf16(af, bf, ha[nt], 0, 0, 0);
      }
    }
    #pragma unroll
    for (int nt = 0; nt < 2; ++nt) {
      int n = hh * 128 + w * 32 + nt * 16 + m;
      float bv = b1_[n];
      #pragma unroll
      for (int r = 0; r < 4; ++r) {
        float vv = ha[nt][r] + bv;
        vv = 0.5f * vv * (1.f + erff(vv * 0.70710678118654752f));
        AH[(quad * 4 + r) * 268 + n] = f2bf(vv);
      }
    }
  }
  // ---- W2: K=256 in two chunks (chunk kb == H half kb)
  f32x4 a2[2] = {zero, zero};
  for (int kb = 0; kb < 2; ++kb) {
    __syncthreads();                   // Blds reads drained + H published
    #pragma unroll
    for (int j = 0; j < 8; ++j) {
      int c = j * 4 + w;
      int r = c * 4 + lrow;
      int jlog = jphys ^ (r & 15);
      __builtin_amdgcn_global_load_lds(
          (const unsigned*)&Wt2[(size_t)r * 256 + kb * 128 + jlog * 8],
          (unsigned*)&Blds[c * 512], 16, 0, 0);
    }
    __syncthreads();
    #pragma unroll
    for (int ks = 0; ks < 4; ++ks) {
      int pc = ((quad + ks * 4) ^ m) * 8;
      short8 af = *(const short8*)&AH[m * 268 + kb * 128 + quad * 8 + ks * 32];
      #pragma unroll
      for (int nt = 0; nt < 2; ++nt) {
        short8 bf = *(const short8*)&Blds[(w * 32 + nt * 16 + m) * 128 + pc];
        a2[nt] = __builtin_amdgcn_mfma_f32_16x16x32_bf16(af, bf, a2[nt], 0, 0, 0);
      }
    }
  }
  // ---- MLP epilogue: residual from registers, single tokens write
  #pragma unroll
  for (int nt = 0; nt < 2; ++nt) {
    int col = w * 32 + nt * 16 + m;
    float bv = b2_[col];
    #pragma unroll
    for (int r = 0; r < 4; ++r) {
      int row = row0 + quad * 4 + r;
      float val = a2[nt][r] + bv + v[nt][r];
      tokens[(size_t)row * DD + col] = val;
      v[nt][r] = val;
    }
  }
  if (ln1g_ == nullptr) {
    // ---- layer-1 tail: decoder-head GEMV fused (tokens . dWc/dWf + bias)
    bool coarse = (rloc < NCc);        // block-uniform (NC multiple of 16)
    const float* dw = coarse ? dWc_ : dWf_;
    float dwv[2];
    #pragma unroll
    for (int nt = 0; nt < 2; ++nt) dwv[nt] = dw[w * 32 + nt * 16 + m];
    #pragma unroll
    for (int r = 0; r < 4; ++r) {
      float s = v[0][r] * dwv[0] + v[1][r] * dwv[1];
      #pragma unroll
      for (int o = 1; o < 16; o <<= 1) s += __shfl_xor(s, o);
      if (m == 0) pls[w][quad * 4 + r] = s;
    }
    __syncthreads();
    if (m == 0 && w == 0) {
      float dbv = coarse ? dbc_[0] : dbf_[0];
      #pragma unroll
      for (int r = 0; r < 4; ++r) {
        int lr = quad * 4 + r;
        hrow[row0 + lr] = pls[0][lr] + pls[1][lr] + pls[2][lr] + pls[3][lr] + dbv;
      }
    }
    return;
  }
  // ---- LN1 stats (layer 0 only)
  #pragma unroll
  for (int r = 0; r < 4; ++r) {
    float s = v[0][r] + v[1][r];
    float q = v[0][r] * v[0][r] + v[1][r] * v[1][r];
    #pragma unroll
    for (int o = 1; o < 16; o <<= 1) { s += __shfl_xor(s, o); q += __shfl_xor(q, o); }
    if (m == 0) {
      int lr = quad * 4 + r;
      pls[w][lr] = s;
      plq[w][lr] = q;
    }
  }
  __syncthreads();   // stats published + W2 Blds reads drained
  // ---- QKV chunk-0 DMA now (overlaps LN1 apply)
  #pragma unroll
  for (int j = 0; j < 8; ++j) {
    int c = j * 4 + w;
    int r = c * 4 + lrow;
    int jlog = jphys ^ (r & 15);
    __builtin_amdgcn_global_load_lds(
        (const unsigned*)&WtQ[(size_t)r * 128 + jlog * 8],
        (unsigned*)&Blds[c * 512], 16, 0, 0);
  }
  #pragma unroll
  for (int r = 0; r < 4; ++r) {
    int lr = quad * 4 + r;
    float S = pls[0][lr] + pls[1][lr] + pls[2][lr] + pls[3][lr];
    float Q = plq[0][lr] + plq[1][lr] + plq[2][lr] + plq[3][lr];
    float mean = S * (1.f / 128.f);
    float var = Q * (1.f / 128.f) - mean * mean;
    float rstd = rsqrtf(var + 1e-5f);
    #pragma unroll
    for (int nt = 0; nt < 2; ++nt) {
      int col = w * 32 + nt * 16 + m;
      Ylds[lr * 136 + col] = f2bf((v[nt][r] - mean) * rstd * ln1g_[col] + ln1b_[col]);
    }
  }
  // ---- next-layer QKV GEMM: 3 chunks of 128 output cols
  for (int c3 = 0; c3 < 3; ++c3) {
    if (c3) {
      __syncthreads();
      #pragma unroll
      for (int j = 0; j < 8; ++j) {
        int c = j * 4 + w;
        int r = c * 4 + lrow;
        int jlog = jphys ^ (r & 15);
        __builtin_amdgcn_global_load_lds(
            (const unsigned*)&WtQ[(size_t)(c3 * 128 + r) * 128 + jlog * 8],
            (unsigned*)&Blds[c * 512], 16, 0, 0);
      }
    }
    __syncthreads();   // DMA drained (+ Ylds published on c3=0)
    f32x4 qa[2] = {zero, zero};
    #pragma unroll
    for (int ks = 0; ks < 4; ++ks) {
      short8 af = *(const short8*)&Ylds[m * 136 + quad * 8 + ks * 32];
      int pc = ((quad + ks * 4) ^ m) * 8;
      #pragma unroll
      for (int nt = 0; nt < 2; ++nt) {
        short8 bf = *(const short8*)&Blds[(w * 32 + nt * 16 + m) * 128 + pc];
        qa[nt] = __builtin_amdgcn_mfma_f32_16x16x32_bf16(af, bf, qa[nt], 0, 0, 0);
      }
    }
    #pragma unroll
    for (int nt = 0; nt < 2; ++nt) {
      int col = c3 * 128 + w * 32 + nt * 16 + m;
      #pragma unroll
      for (int r = 0; r < 4; ++r) {
        int row = row0 + quad * 4 + r;
        qkvb[(size_t)row * 384 + col] = f2bf(qa[nt][r]);
      }
    }
  }
}

// ---------------- flash attention: split-K (SPLIT=2), fixed-max softmax,
// double-buffered K/V (one barrier/stage, prefetch issued before compute so
// K-DMA + V-load latency hides under MFMA+softmax), XCD-chunked block swizzle
// (all 40 blocks of one (b,h) land on XCD g%8 -> K/V panel L2-resident once).
__global__ __launch_bounds__(256) void k_attn4(const short* __restrict__ qkv,
    short* __restrict__ Opart, float* __restrict__ Lpart) {
  __shared__ short Ks[2][64 * 32];   // [key][d], DMA, chunk swizzle f(k)=(k>>1)&3
  __shared__ short Vt[2][32 * 74];   // [d][key], stride 74 (free scatter+gather)
  __shared__ short Pl[4][16 * 74];   // per-wave P [q][key]

  // XCD-chunked decode: hw id = k*32 + g  (g = (b,h) group, k = 40 tiles)
  int hid = blockIdx.x;
  int g = hid & 31;                  // (b,h) group 0..31
  int k = hid >> 5;                  // 0..39
  int b = g >> 2, h = g & 3;         // HEADS = 4
  int qt = k / SPLIT, sk = k % SPLIT;
  size_t lid = ((size_t)g * NQT + qt) * SPLIT + sk;   // logical output slot
  int t = threadIdx.x;
  int lane = t & 63, w = t >> 6;
  int m = lane & 15, quad = lane >> 4;
  int q0 = qt * 64 + w * 16;

  const float scale = 0.17677669529663687f;  // 1/sqrt(32), folded into Q
  short8 qraw = *(const short8*)(qkv + ((size_t)(b * NTOK) + q0 + m) * 384 + h * HD + quad * 8);
  short8 qf;
  #pragma unroll
  for (int j = 0; j < 8; ++j) qf[j] = f2bf(bf2f(qraw[j]) * scale);

  f32x4 zero = {0.f, 0.f, 0.f, 0.f};
  f32x4 Oacc[2] = {zero, zero};
  float psum[4] = {0.f, 0.f, 0.f, 0.f};

  int skey = t >> 2, sdseg = t & 3;  // staging: key 0..63, 8 dims each
  int jlogK = sdseg ^ ((skey >> 1) & 3);
  const short* kstage = qkv + ((size_t)(b * NTOK) + skey) * 384 + 128 + h * HD + jlogK * 8;
  const short* vstage = qkv + ((size_t)(b * NTOK) + skey) * 384 + 256 + h * HD + sdseg * 8;
  int kswz = (quad ^ ((m >> 1) & 3)) * 8;   // read-side physical chunk offset

  int s0 = sk * NSTG;
  // ---- prologue: stage s0 into buffer 0
  __builtin_amdgcn_global_load_lds((const unsigned*)(kstage + (size_t)s0 * 64 * 384),
                                   (unsigned*)&Ks[0][w * 512], 16, 0, 0);
  {
    short8 vf = *(const short8*)(vstage + (size_t)s0 * 64 * 384);
    #pragma unroll
    for (int j = 0; j < 8; ++j) Vt[0][(sdseg * 8 + j) * 74 + skey] = vf[j];
  }
  __syncthreads();   // K DMA + V scatter of stage 0 complete

  for (int i = 0; i < NSTG; ++i) {
    int cur = i & 1;
    short8 vf;
    if (i + 1 < NSTG) {
      // prefetch next stage BEFORE compute: K-DMA into other buffer, V to regs
      __builtin_amdgcn_global_load_lds(
          (const unsigned*)(kstage + (size_t)(s0 + i + 1) * 64 * 384),
          (unsigned*)&Ks[cur ^ 1][w * 512], 16, 0, 0);
      vf = *(const short8*)(vstage + (size_t)(s0 + i + 1) * 64 * 384);
    }

    // S = Q K^T (C-layout: row=4*quad+reg, col=m); Q pre-scaled
    f32x4 sc[4];
    #pragma unroll
    for (int ct = 0; ct < 4; ++ct) {
      short8 kfrag = *(const short8*)&Ks[cur][(ct * 16 + m) * 32 + kswz];
      sc[ct] = __builtin_amdgcn_mfma_f32_16x16x32_bf16(qf, kfrag, zero, 0, 0, 0);
    }
    // fixed-max softmax: p = exp(s); l accumulated from TRUNCATED p (bias-free)
    #pragma unroll
    for (int ct = 0; ct < 4; ++ct)
      #pragma unroll
      for (int r = 0; r < 4; ++r) {
        float p = __expf(sc[ct][r]);
        unsigned u = __builtin_bit_cast(unsigned, p);
        psum[r] += __builtin_bit_cast(float, u & 0xffff0000u);
        Pl[w][(quad * 4 + r) * 74 + ct * 16 + m] = (short)(u >> 16);
      }
    // O += P @ V
    #pragma unroll
    for (int ks = 0; ks < 2; ++ks) {
      short8 pfrag = *(const short8*)&Pl[w][m * 74 + ks * 32 + quad * 8];
      #pragma unroll
      for (int nt = 0; nt < 2; ++nt) {
        short8 vfrag = *(const short8*)&Vt[cur][(nt * 16 + m) * 74 + ks * 32 + quad * 8];
        Oacc[nt] = __builtin_amdgcn_mfma_f32_16x16x32_bf16(pfrag, vfrag, Oacc[nt], 0, 0, 0);
      }
    }
    if (i + 1 < NSTG) {
      // write-late: scatter prefetched V into the other buffer
      #pragma unroll
      for (int j = 0; j < 8; ++j) Vt[cur ^ 1][(sdseg * 8 + j) * 74 + skey] = vf[j];
    }
    __syncthreads();   // next-stage K DMA drained + V scatter published
  }
  // single final ladder per row; write partial O (unnormalized) + l
  #pragma unroll
  for (int r = 0; r < 4; ++r) {
    float ssum = psum[r];
    #pragma unroll
    for (int o = 1; o < 16; o <<= 1) ssum += __shfl_xor(ssum, o);
    int qloc = w * 16 + quad * 4 + r;
    #pragma unroll
    for (int nt = 0; nt < 2; ++nt)
      Opart[lid * 2048 + qloc * 32 + nt * 16 + m] = f2bf(Oacc[nt][r]);
    if (m == 0) Lpart[lid * 64 + qloc] = ssum;
  }
}

// ---------------- fused decoder: reads precomputed head scalars (hrow),
// scatter + bilinear + conv3x3+relu+conv3x3 — one block per image
__global__ __launch_bounds__(1024) void k_decoder(const float* __restrict__ hrow,
    const float* __restrict__ msort, const int* __restrict__ order,
    const float* __restrict__ fW1, const float* __restrict__ fb1,
    const float* __restrict__ fW2, const float* __restrict__ fb2,
    float* __restrict__ outp) {
  int b = blockIdx.x;
  int t = threadIdx.x;
  __shared__ float cmap[NCc];
  __shared__ float fmap[1024];
  __shared__ float cup[1024];
  __shared__ float hb[2][1024];
  fmap[order[b * NFf + t]] = hrow[b * NTOK + NCc + t] * msort[b * NFf + t];
  if (t < NCc) cmap[t] = hrow[b * NTOK + t];
  __syncthreads();
  int y = t >> 5, x = t & 31;
  {
    float ys = y * (15.f / 31.f);
    float xs = x * (15.f / 31.f);
    int y0 = (int)floorf(ys); int y1 = min(y0 + 1, 15); float wy = ys - (float)y0;
    int x0 = (int)floorf(xs); int x1 = min(x0 + 1, 15); float wx = xs - (float)x0;
    cup[t] = cmap[y0 * 16 + x0] * (1.f - wy) * (1.f - wx)
           + cmap[y0 * 16 + x1] * (1.f - wy) * wx
           + cmap[y1 * 16 + x0] * wy * (1.f - wx)
           + cmap[y1 * 16 + x1] * wy * wx;
  }
  __syncthreads();
  for (int oc = 0; oc < 2; ++oc) {
    float a = fb1[oc];
    #pragma unroll
    for (int ic = 0; ic < 2; ++ic)
      #pragma unroll
      for (int ky = 0; ky < 3; ++ky)
        #pragma unroll
        for (int kx = 0; kx < 3; ++kx) {
          int yy = y + ky - 1, xx = x + kx - 1;
          float v = 0.f;
          if (yy >= 0 && yy < 32 && xx >= 0 && xx < 32)
            v = ic == 0 ? cup[yy * 32 + xx] : fmap[yy * 32 + xx];
          a += v * fW1[((oc * 2 + ic) * 3 + ky) * 3 + kx];
        }
    hb[oc][t] = fmaxf(a, 0.f);
  }
  __syncthreads();
  float a = fb2[0];
  #pragma unroll
  for (int ic = 0; ic < 2; ++ic)
    #pragma unroll
    for (int ky = 0; ky < 3; ++ky)
      #pragma unroll
      for (int kx = 0; kx < 3; ++kx) {
        int yy = y + ky - 1, xx = x + kx - 1;
        float v = (yy >= 0 && yy < 32 && xx >= 0 && xx < 32)
                      ? hb[ic][yy * 32 + xx] : 0.f;
        a += v * fW2[(ic * 3 + ky) * 3 + kx];
      }
  outp[b * 1024 + t] = a;
}

extern "C" void kernel_launch(void* const* d_in, const int* in_sizes, int n_in,
                              void* d_out, int out_size, void* d_ws, size_t ws_size,
                              hipStream_t stream) {
  const float* x    = (const float*)d_in[0];
  const float* Wpc  = (const float*)d_in[1];
  const float* bpc  = (const float*)d_in[2];
  const float* Wpf  = (const float*)d_in[3];
  const float* bpf  = (const float*)d_in[4];
  const float* te   = (const float*)d_in[5];
  const float* ln1g = (const float*)d_in[6];
  const float* ln1b = (const float*)d_in[7];
  const float* Wqkv = (const float*)d_in[8];
  const float* Wo   = (const float*)d_in[9];
  const float* bo   = (const float*)d_in[10];
  const float* ln2g = (const float*)d_in[11];
  const float* ln2b = (const float*)d_in[12];
  const float* W1   = (const float*)d_in[13];
  const float* b1   = (const float*)d_in[14];
  const float* W2   = (const float*)d_in[15];
  const float* b2   = (const float*)d_in[16];
  const float* dWc  = (const float*)d_in[17];
  const float* dbc  = (const float*)d_in[18];
  const float* dWf  = (const float*)d_in[19];
  const float* dbf  = (const float*)d_in[20];
  const float* fW1  = (const float*)d_in[21];
  const float* fb1  = (const float*)d_in[22];
  const float* fW2  = (const float*)d_in[23];
  const float* fb2  = (const float*)d_in[24];

  char* ws = (char*)d_ws;
  float* tokens = (float*)ws;                 ws += 1310720 * 4;   // fp32 [B*N,128]
  float* fineb  = (float*)ws;                 ws += 1048576 * 4;   // fp32 [B*NF,128]
  short* qkvb   = (short*)ws;                 ws += 3932160 * 2;   // bf16 [B*N,384]
  short* Opart  = (short*)ws;                 ws += (size_t)(Bx * HEADS * NQT * SPLIT) * 2048 * 2;
  float* Lpart  = (float*)ws;                 ws += (size_t)(Bx * HEADS * NQT * SPLIT) * 64 * 4;
  short* WtQKV  = (short*)ws;                 ws += 98304 * 2;     // [L][384][128]
  short* WtO    = (short*)ws;                 ws += 32768 * 2;     // [L][128][128]
  short* Wt1    = (short*)ws;                 ws += 65536 * 2;     // [L][256][128]
  short* Wt2    = (short*)ws;                 ws += 65536 * 2;     // [L][128][256]
  float* ebuf   = (float*)ws;                 ws += 8192 * 4;
  float* msort  = (float*)ws;                 ws += 8192 * 4;
  int*   order  = (int*)ws;                   ws += 8192 * 4;
  float* hrow   = (float*)ws;                 ws += 10240 * 4;     // decoder-head scalars

  const int M = Bx * NTOK;                    // 10240

  k_prologue<<<6656, 256, 0, stream>>>(x, Wpc, bpc, Wpf, bpf, te, Wqkv, Wo, W1, W2,
                                       WtQKV, WtO, Wt1, Wt2, ebuf, tokens, fineb);
  k_edge_sort<<<Bx, 1024, 0, stream>>>(ebuf, order, msort);
  k_gather_qkv<<<M / 16, 256, 0, stream>>>(tokens, fineb, order, msort, te,
                                           ln1g, ln1b, WtQKV, qkvb);

  // layer 0: attn -> fused[Wo+LN2+MLP+LN1+QKV(l1)]
  k_attn4<<<Bx * HEADS * NQT * SPLIT, 256, 0, stream>>>(qkvb, Opart, Lpart);
  k_fused<<<M / 16, 256, 0, stream>>>(
      Opart, Lpart, WtO, bo, ln2g, ln2b,
      Wt1, b1, Wt2, b2, tokens,
      ln1g + DD, ln1b + DD, WtQKV + 49152, qkvb,
      nullptr, nullptr, nullptr, nullptr, nullptr);

  // layer 1: attn -> fused[Wo+LN2+MLP+decoder-head]
  k_attn4<<<Bx * HEADS * NQT * SPLIT, 256, 0, stream>>>(qkvb, Opart, Lpart);
  k_fused<<<M / 16, 256, 0, stream>>>(
      Opart, Lpart, WtO + 16384, bo + DD, ln2g + DD, ln2b + DD,
      Wt1 + 32768, b1 + 256, Wt2 + 32768, b2 + DD, tokens,
      nullptr, nullptr, nullptr, nullptr,
      dWc, dbc, dWf, dbf, hrow);

  k_decoder<<<Bx, 1024, 0, stream>>>(hrow, msort, order,
                                     fW1, fb1, fW2, fb2, (float*)d_out);
}